// Round 12
// baseline (181.852 us; speedup 1.0000x reference)
//
#include <hip/hip_runtime.h>
#include <math.h>

#define N_NODES 100000
#define N_EDGES 1600000
#define F0 32
#define F1 16
#define F2 8
#define NCLS 6
#define NGRAPH 64

#define BSH  8         // bucket = 256 nodes (power of 2 -> exact split)
#define BSZ  256       // nodes per bucket
#define NBUK 391       // ceil(100000/256)
#define CAPB 4608      // edge cap per bucket region (mean 4092, sigma 64 -> +8 sigma)
#define EPB  4093      // edges per xpart chunk: ceil(1600000/391)
#define NPW  257       // np_g stride per bucket

// ========== kernel 1: fused node-transform (x@W1a) + edge partition ==========
__global__ __launch_bounds__(256) void xpart_k(
    const float* __restrict__ x, const float* __restrict__ W1a,
    float* __restrict__ xw1, const int* __restrict__ ei,
    int* __restrict__ gcursor, int* __restrict__ pairs) {
    __shared__ float sW[F0 * F1];
    __shared__ int hist[512];
    __shared__ int cur[512];
    __shared__ int sdst[EPB];
    int t = threadIdx.x, c = blockIdx.x;
    for (int i = t; i < F0 * F1; i += 256) sW[i] = W1a[i];
    hist[t] = 0; hist[t + 256] = 0;
    __syncthreads();

    // --- stage dst + chunk histogram ---
    int base = c * EPB, eend = min(base + EPB, N_EDGES);
    for (int i = base + t; i < eend; i += 256) {
        int d = ei[N_EDGES + i];
        sdst[i - base] = d;
        atomicAdd(&hist[d >> BSH], 1);
    }

    // --- node projection (independent work, overlaps hist latency) ---
    int n = c * 256 + t;
    if (n < N_NODES) {
        const float4* xp = reinterpret_cast<const float4*>(x) + n * (F0 / 4);
        float xi[F0];
#pragma unroll
        for (int q = 0; q < F0 / 4; q++) {
            float4 v = xp[q];
            xi[4*q] = v.x; xi[4*q+1] = v.y; xi[4*q+2] = v.z; xi[4*q+3] = v.w;
        }
        float o[F1];
#pragma unroll
        for (int j = 0; j < F1; j++) {
            float s = 0.0f;
#pragma unroll
            for (int k = 0; k < F0; k++) s += xi[k] * sW[k * F1 + j];
            o[j] = s;
        }
        float4* op = reinterpret_cast<float4*>(xw1) + n * (F1 / 4);
        op[0] = make_float4(o[0],  o[1],  o[2],  o[3]);
        op[1] = make_float4(o[4],  o[5],  o[6],  o[7]);
        op[2] = make_float4(o[8],  o[9],  o[10], o[11]);
        op[3] = make_float4(o[12], o[13], o[14], o[15]);
    }
    __syncthreads();

    // --- reserve contiguous sub-range per bucket (strided: NBUK > 256) ---
    for (int b = t; b < 512; b += 256) {
        int cnt = (b < NBUK) ? hist[b] : 0;
        cur[b] = b * CAPB + (cnt ? atomicAdd(&gcursor[b], cnt) : 0);
    }
    __syncthreads();

    // --- scatter packed (dl<<17 | src) into bucket regions (guarded) ---
    for (int i = base + t; i < eend; i += 256) {
        int s = ei[i];
        int d = sdst[i - base];
        int b = d >> BSH;
        int pos = atomicAdd(&cur[b], 1);
        if (pos < (b + 1) * CAPB)                 // overflow guard (~never taken)
            pairs[pos] = ((d & (BSZ - 1)) << 17) | s;
    }
}

// ======= kernel 2: lean per-bucket counting sort -> srcs + np_g =======
// No weights / no MLP: ~5 KB LDS, sort only (un-fused from gin1 -> gather
// phase no longer trapped at 1.5 blocks/CU behind a 25 KB LDS sort)
__global__ __launch_bounds__(256) void passB_k(
    const int* __restrict__ pairs, const int* __restrict__ gcursor,
    int* __restrict__ srcs, int* __restrict__ np_g) {
    __shared__ int hist[256];
    __shared__ int sbuf[2][256];
    __shared__ int cur[256];
    int t = threadIdx.x, b = blockIdx.x;
    hist[t] = 0;
    __syncthreads();

    int cnt = min(gcursor[b], CAPB);
    int pb = b * CAPB;
    for (int i = t; i < cnt; i += 256)
        atomicAdd(&hist[pairs[pb + i] >> 17], 1);
    __syncthreads();
    sbuf[0][t] = hist[t];
    __syncthreads();
    int cb = 0;
    for (int off = 1; off < 256; off <<= 1) {
        int v = sbuf[cb][t];
        if (t >= off) v += sbuf[cb][t - off];
        sbuf[cb ^ 1][t] = v;
        cb ^= 1;
        __syncthreads();
    }
    int excl = sbuf[cb][t] - hist[t];
    cur[t] = excl;
    np_g[b * NPW + t] = excl;
    if (t == 0) np_g[b * NPW + BSZ] = cnt;
    __syncthreads();
    for (int i = t; i < cnt; i += 256) {
        int p = pairs[pb + i];
        int pos = atomicAdd(&cur[p >> 17], 1);
        srcs[pb + pos] = p & 0x1FFFF;             // bucket-local 4B writes
    }
}

#define ACC16(P) { float4 q0 = (P)[0], q1 = (P)[1], q2 = (P)[2], q3 = (P)[3]; \
    acc[0] += q0.x;  acc[1] += q0.y;  acc[2]  += q0.z;  acc[3]  += q0.w;      \
    acc[4] += q1.x;  acc[5] += q1.y;  acc[6]  += q1.z;  acc[7]  += q1.w;      \
    acc[8] += q2.x;  acc[9] += q2.y;  acc[10] += q2.z;  acc[11] += q2.w;      \
    acc[12] += q3.x; acc[13] += q3.y; acc[14] += q3.z;  acc[15] += q3.w; }

// ==== kernel 3: layer-1 gather (2 lanes/node, high occupancy) + MLP1 + W2a ====
// 782 blocks x 256 thr, ~2 KB LDS -> 8 blocks/CU headroom (same shape as gin2pool)
__global__ __launch_bounds__(256) void gin1_k(
    const float* __restrict__ xw1, const int* __restrict__ np_g,
    const int* __restrict__ srcs, const float* __restrict__ b1a,
    const float* __restrict__ W1b, const float* __restrict__ b1b,
    const float* __restrict__ W2a, float* __restrict__ h1w) {
    __shared__ float sW1b[F1 * F1];
    __shared__ float sW2a[F1 * F2];
    __shared__ float sb1a[F1], sb1b[F1];
    int t = threadIdx.x;
    if (t < F1 * F1) sW1b[t] = W1b[t];
    if (t < F1 * F2) sW2a[t] = W2a[t];
    if (t < F1) { sb1a[t] = b1a[t]; sb1b[t] = b1b[t]; }
    __syncthreads();

    int slot = t >> 1, h = t & 1;
    int n = blockIdx.x * 128 + slot;
    if (n >= N_NODES) return;

    int b  = n >> BSH;
    int sl = n & (BSZ - 1);
    int pb = b * CAPB;
    float acc[F1];
#pragma unroll
    for (int k = 0; k < F1; k++) acc[k] = 0.0f;
    const float4* X = reinterpret_cast<const float4*>(xw1);
    int e  = pb + np_g[b * NPW + sl] + h;
    int e1 = pb + np_g[b * NPW + sl + 1];
    for (; e + 6 < e1; e += 8) {               // 4 rows in flight per lane
        const float4* p0 = X + srcs[e + 0] * 4;
        const float4* p1 = X + srcs[e + 2] * 4;
        const float4* p2 = X + srcs[e + 4] * 4;
        const float4* p3 = X + srcs[e + 6] * 4;
        ACC16(p0); ACC16(p1); ACC16(p2); ACC16(p3);
    }
    for (; e < e1; e += 2) { const float4* p0 = X + srcs[e] * 4; ACC16(p0); }
    if (h == 0) { const float4* pn = X + n * 4; ACC16(pn); }   // self term once

    // pair-combine: lanes 2s/2s+1 are wave-internal
#pragma unroll
    for (int k = 0; k < F1; k++) acc[k] += __shfl_xor(acc[k], 1);

    if (h == 0) {
        float u[F1];
#pragma unroll
        for (int k = 0; k < F1; k++) u[k] = fmaxf(acc[k] + sb1a[k], 0.0f);
        float hh[F1];
#pragma unroll
        for (int j = 0; j < F1; j++) {
            float s = sb1b[j];
#pragma unroll
            for (int k = 0; k < F1; k++) s += u[k] * sW1b[k * F1 + j];
            hh[j] = fmaxf(s, 0.0f);            // relu∘relu = relu
        }
        float o[F2];
#pragma unroll
        for (int j = 0; j < F2; j++) {
            float s = 0.0f;
#pragma unroll
            for (int k = 0; k < F1; k++) s += hh[k] * sW2a[k * F2 + j];
            o[j] = s;
        }
        float4* hp = reinterpret_cast<float4*>(h1w) + n * 2;
        hp[0] = make_float4(o[0], o[1], o[2], o[3]);
        hp[1] = make_float4(o[4], o[5], o[6], o[7]);
    }
}

#define ACC8(P) { float4 q0 = (P)[0], q1 = (P)[1];                        \
    acc[0] += q0.x; acc[1] += q0.y; acc[2] += q0.z; acc[3] += q0.w;       \
    acc[4] += q1.x; acc[5] += q1.y; acc[6] += q1.z; acc[7] += q1.w; }

// ==== kernel 4: layer-2 gather (2 lanes/node) + MLP2 + fused mean-pool ====
__global__ __launch_bounds__(256) void gin2pool_k(
    const float* __restrict__ h1w, const int* __restrict__ np_g,
    const int* __restrict__ srcs, const float* __restrict__ b2a,
    const float* __restrict__ W2b, const float* __restrict__ b2b,
    const int* __restrict__ batch, float* __restrict__ gsum,
    float* __restrict__ gcnt) {
    __shared__ float sW2b[F2 * F2];
    __shared__ float sb2a[F2];
    __shared__ float sb2b[F2];
    __shared__ float ls[NGRAPH * F2];   // 512 > blockDim -> strided loops (r5 lesson)
    __shared__ float lc[NGRAPH];
    int t = threadIdx.x;
    if (t < F2 * F2) sW2b[t] = W2b[t];
    if (t < F2) { sb2a[t] = b2a[t]; sb2b[t] = b2b[t]; }
    for (int i = t; i < NGRAPH * F2; i += 256) ls[i] = 0.0f;
    if (t < NGRAPH) lc[t] = 0.0f;
    __syncthreads();

    int slot = t >> 1, h = t & 1;
    int n = blockIdx.x * 128 + slot;
    if (n < N_NODES) {
        int b  = n >> BSH;
        int sl = n & (BSZ - 1);
        int pb = b * CAPB;
        float acc[F2];
#pragma unroll
        for (int k = 0; k < F2; k++) acc[k] = 0.0f;
        const float4* H = reinterpret_cast<const float4*>(h1w);
        int e  = pb + np_g[b * NPW + sl] + h;
        int e1 = pb + np_g[b * NPW + sl + 1];
        for (; e + 6 < e1; e += 8) {
            const float4* p0 = H + srcs[e + 0] * 2;
            const float4* p1 = H + srcs[e + 2] * 2;
            const float4* p2 = H + srcs[e + 4] * 2;
            const float4* p3 = H + srcs[e + 6] * 2;
            ACC8(p0); ACC8(p1); ACC8(p2); ACC8(p3);
        }
        for (; e < e1; e += 2) { const float4* p0 = H + srcs[e] * 2; ACC8(p0); }
        if (h == 0) { const float4* pn = H + n * 2; ACC8(pn); }    // self term once

#pragma unroll
        for (int k = 0; k < F2; k++) acc[k] += __shfl_xor(acc[k], 1);

        if (h == 0) {
            float u[F2];
#pragma unroll
            for (int k = 0; k < F2; k++) u[k] = fmaxf(acc[k] + sb2a[k], 0.0f);
            float v[F2];
#pragma unroll
            for (int j = 0; j < F2; j++) {
                float s = sb2b[j];
#pragma unroll
                for (int k = 0; k < F2; k++) s += u[k] * sW2b[k * F2 + j];
                v[j] = fmaxf(s, 0.0f);
            }
            int g = batch[n];
#pragma unroll
            for (int j = 0; j < F2; j++) atomicAdd(&ls[g * F2 + j], v[j]);
            atomicAdd(&lc[g], 1.0f);
        }
    }
    __syncthreads();
    for (int i = t; i < NGRAPH * F2; i += 256)
        if (ls[i] != 0.0f) atomicAdd(&gsum[i], ls[i]);
    if (t < NGRAPH && lc[t] != 0.0f) atomicAdd(&gcnt[t], lc[t]);
}

// ---------------- final: pooled -> FC -> log_softmax ----------------
__global__ void final_k(const float* __restrict__ gsum,
                        const float* __restrict__ gcnt,
                        const float* __restrict__ Wfc, const float* __restrict__ bfc,
                        float* __restrict__ out) {
    int g = threadIdx.x;
    if (g >= NGRAPH) return;
    float cnt = fmaxf(gcnt[g], 1.0f);
    float p[F2];
#pragma unroll
    for (int f = 0; f < F2; f++) p[f] = gsum[g * F2 + f] / cnt;
    float l[NCLS];
#pragma unroll
    for (int c = 0; c < NCLS; c++) {
        float s = bfc[c];
#pragma unroll
        for (int f = 0; f < F2; f++) s += p[f] * Wfc[f * NCLS + c];
        l[c] = s;
    }
    float m = -INFINITY;
#pragma unroll
    for (int c = 0; c < NCLS; c++) m = fmaxf(m, l[c]);
    float s = 0.0f;
#pragma unroll
    for (int c = 0; c < NCLS; c++) s += expf(l[c] - m);
    float lse = m + logf(s);
#pragma unroll
    for (int c = 0; c < NCLS; c++) out[g * NCLS + c] = l[c] - lse;
}

extern "C" void kernel_launch(void* const* d_in, const int* in_sizes, int n_in,
                              void* d_out, int out_size, void* d_ws, size_t ws_size,
                              hipStream_t stream) {
    const float* x    = (const float*)d_in[0];
    const int*   ei   = (const int*)d_in[1];   // [2, N_EDGES]
    const int*   batch= (const int*)d_in[2];   // [N_NODES], sorted
    const float* W1a  = (const float*)d_in[3];
    const float* b1a  = (const float*)d_in[4];
    const float* W1b  = (const float*)d_in[5];
    const float* b1b  = (const float*)d_in[6];
    const float* W2a  = (const float*)d_in[7];
    const float* b2a  = (const float*)d_in[8];
    const float* W2b  = (const float*)d_in[9];
    const float* b2b  = (const float*)d_in[10];
    const float* Wfc  = (const float*)d_in[11];
    const float* bfc  = (const float*)d_in[12];
    float* out = (float*)d_out;

    // workspace layout (4-byte units), ~24 MB
    float* ws      = (float*)d_ws;
    float* xw1     = ws;                                   // N_NODES*16
    float* h1w     = xw1 + (size_t)N_NODES * F1;           // N_NODES*8
    int*   pairs   = (int*)(h1w + (size_t)N_NODES * F2);   // NBUK*CAPB = 1801728
    int*   srcs    = pairs + (size_t)NBUK * CAPB;          // NBUK*CAPB
    int*   np_g    = srcs + (size_t)NBUK * CAPB;           // NBUK*NPW = 100487
    int*   gcursor = np_g + (size_t)NBUK * NPW + 9;        // 512   (memset)
    float* gsum    = (float*)(gcursor + 512);              // 512   (memset)
    float* gcnt    = gsum + NGRAPH * F2;                   // 64    (memset)

    // one tiny memset: gcursor + gsum + gcnt adjacent
    hipMemsetAsync(gcursor, 0, (512 + NGRAPH * F2 + NGRAPH) * sizeof(int), stream);

    xpart_k<<<NBUK, 256, 0, stream>>>(x, W1a, xw1, ei, gcursor, pairs);
    passB_k<<<NBUK, 256, 0, stream>>>(pairs, gcursor, srcs, np_g);
    gin1_k<<<(N_NODES + 127) / 128, 256, 0, stream>>>(xw1, np_g, srcs,
                                                      b1a, W1b, b1b, W2a, h1w);
    gin2pool_k<<<(N_NODES + 127) / 128, 256, 0, stream>>>(h1w, np_g, srcs,
                                                          b2a, W2b, b2b, batch,
                                                          gsum, gcnt);
    final_k<<<1, 64, 0, stream>>>(gsum, gcnt, Wfc, bfc, out);
}

// Round 13
// 179.534 us; speedup vs baseline: 1.0129x; 1.0129x over previous
//
#include <hip/hip_runtime.h>
#include <math.h>

#define N_NODES 100000
#define N_EDGES 1600000
#define F0 32
#define F1 16
#define F2 8
#define NCLS 6
#define NGRAPH 64

#define BSH  8         // bucket = 256 nodes (power of 2 -> exact split)
#define BSZ  256       // nodes per bucket
#define NBUK 391       // ceil(100000/256)
#define CAPB 4608      // edge cap per bucket region (mean 4092, sigma 64 -> +8 sigma)
#define EPB  4093      // edges per xpart chunk: ceil(1600000/391)
#define NPW  257       // np_g stride per bucket

// ========== kernel 1: fused node-transform (x@W1a) + edge partition ==========
__global__ __launch_bounds__(256) void xpart_k(
    const float* __restrict__ x, const float* __restrict__ W1a,
    float* __restrict__ xw1, const int* __restrict__ ei,
    int* __restrict__ gcursor, int* __restrict__ pairs) {
    __shared__ float sW[F0 * F1];
    __shared__ int hist[512];
    __shared__ int cur[512];
    __shared__ int sdst[EPB];
    int t = threadIdx.x, c = blockIdx.x;
    for (int i = t; i < F0 * F1; i += 256) sW[i] = W1a[i];
    hist[t] = 0; hist[t + 256] = 0;
    __syncthreads();

    // --- stage dst + chunk histogram ---
    int base = c * EPB, eend = min(base + EPB, N_EDGES);
    for (int i = base + t; i < eend; i += 256) {
        int d = ei[N_EDGES + i];
        sdst[i - base] = d;
        atomicAdd(&hist[d >> BSH], 1);
    }

    // --- node projection (independent work, overlaps hist latency) ---
    int n = c * 256 + t;
    if (n < N_NODES) {
        const float4* xp = reinterpret_cast<const float4*>(x) + n * (F0 / 4);
        float xi[F0];
#pragma unroll
        for (int q = 0; q < F0 / 4; q++) {
            float4 v = xp[q];
            xi[4*q] = v.x; xi[4*q+1] = v.y; xi[4*q+2] = v.z; xi[4*q+3] = v.w;
        }
        float o[F1];
#pragma unroll
        for (int j = 0; j < F1; j++) {
            float s = 0.0f;
#pragma unroll
            for (int k = 0; k < F0; k++) s += xi[k] * sW[k * F1 + j];
            o[j] = s;
        }
        float4* op = reinterpret_cast<float4*>(xw1) + n * (F1 / 4);
        op[0] = make_float4(o[0],  o[1],  o[2],  o[3]);
        op[1] = make_float4(o[4],  o[5],  o[6],  o[7]);
        op[2] = make_float4(o[8],  o[9],  o[10], o[11]);
        op[3] = make_float4(o[12], o[13], o[14], o[15]);
    }
    __syncthreads();

    // --- reserve contiguous sub-range per bucket (strided: NBUK > 256) ---
    for (int b = t; b < 512; b += 256) {
        int cnt = (b < NBUK) ? hist[b] : 0;
        cur[b] = b * CAPB + (cnt ? atomicAdd(&gcursor[b], cnt) : 0);
    }
    __syncthreads();

    // --- scatter packed (dl<<17 | src) into bucket regions (guarded) ---
    for (int i = base + t; i < eend; i += 256) {
        int s = ei[i];
        int d = sdst[i - base];
        int b = d >> BSH;
        int pos = atomicAdd(&cur[b], 1);
        if (pos < (b + 1) * CAPB)                 // overflow guard (~never taken)
            pairs[pos] = ((d & (BSZ - 1)) << 17) | s;
    }
}

// ======= kernel 2: lean per-bucket counting sort -> srcs + np_g =======
__global__ __launch_bounds__(256) void passB_k(
    const int* __restrict__ pairs, const int* __restrict__ gcursor,
    int* __restrict__ srcs, int* __restrict__ np_g) {
    __shared__ int hist[256];
    __shared__ int sbuf[2][256];
    __shared__ int cur[256];
    int t = threadIdx.x, b = blockIdx.x;
    hist[t] = 0;
    __syncthreads();

    int cnt = min(gcursor[b], CAPB);
    int pb = b * CAPB;
    for (int i = t; i < cnt; i += 256)
        atomicAdd(&hist[pairs[pb + i] >> 17], 1);
    __syncthreads();
    sbuf[0][t] = hist[t];
    __syncthreads();
    int cb = 0;
    for (int off = 1; off < 256; off <<= 1) {
        int v = sbuf[cb][t];
        if (t >= off) v += sbuf[cb][t - off];
        sbuf[cb ^ 1][t] = v;
        cb ^= 1;
        __syncthreads();
    }
    int excl = sbuf[cb][t] - hist[t];
    cur[t] = excl;
    np_g[b * NPW + t] = excl;
    if (t == 0) np_g[b * NPW + BSZ] = cnt;
    __syncthreads();
    for (int i = t; i < cnt; i += 256) {
        int p = pairs[pb + i];
        int pos = atomicAdd(&cur[p >> 17], 1);
        srcs[pb + pos] = p & 0x1FFFF;             // bucket-local 4B writes
    }
}

// ==== kernel 3: layer-1 gather, 4 LANES PER NODE (1 coalesced 64B req/edge) ====
// lane q of group loads float4 #q of the SAME neighbor row; lane owns feats
// 4q..4q+3 (no reduce for sum). MLP: per-lane partials + 2 shfl_xor rounds.
__global__ __launch_bounds__(256) void gin1_k(
    const float* __restrict__ xw1, const int* __restrict__ np_g,
    const int* __restrict__ srcs, const float* __restrict__ b1a,
    const float* __restrict__ W1b, const float* __restrict__ b1b,
    const float* __restrict__ W2a, float* __restrict__ h1w) {
    __shared__ float sW1b[F1 * F1];
    __shared__ float sW2a[F1 * F2];
    __shared__ float sb1a[F1], sb1b[F1];
    int t = threadIdx.x;
    if (t < F1 * F1) sW1b[t] = W1b[t];
    if (t < F1 * F2) sW2a[t] = W2a[t];
    if (t < F1) { sb1a[t] = b1a[t]; sb1b[t] = b1b[t]; }
    __syncthreads();

    int q = t & 3, slot = t >> 2;                 // 64 nodes per block
    int n = blockIdx.x * 64 + slot;
    if (n >= N_NODES) return;
    int b = n >> BSH, sl = n & (BSZ - 1);
    int pb = b * CAPB;
    int e  = pb + np_g[b * NPW + sl];
    int e1 = pb + np_g[b * NPW + sl + 1];

    const float4* X = reinterpret_cast<const float4*>(xw1);
    float a0 = 0.0f, a1 = 0.0f, a2 = 0.0f, a3 = 0.0f;
    for (; e + 4 <= e1; e += 4) {                 // 4 line-requests in flight
        int s0 = srcs[e], s1 = srcs[e+1], s2 = srcs[e+2], s3 = srcs[e+3];
        float4 v0 = X[s0 * 4 + q];
        float4 v1 = X[s1 * 4 + q];
        float4 v2 = X[s2 * 4 + q];
        float4 v3 = X[s3 * 4 + q];
        a0 += v0.x + v1.x + v2.x + v3.x;
        a1 += v0.y + v1.y + v2.y + v3.y;
        a2 += v0.z + v1.z + v2.z + v3.z;
        a3 += v0.w + v1.w + v2.w + v3.w;
    }
    for (; e < e1; e++) {
        float4 v = X[srcs[e] * 4 + q];
        a0 += v.x; a1 += v.y; a2 += v.z; a3 += v.w;
    }
    { float4 v = X[n * 4 + q]; a0 += v.x; a1 += v.y; a2 += v.z; a3 += v.w; } // self

    float u0 = fmaxf(a0 + sb1a[4*q + 0], 0.0f);
    float u1 = fmaxf(a1 + sb1a[4*q + 1], 0.0f);
    float u2 = fmaxf(a2 + sb1a[4*q + 2], 0.0f);
    float u3 = fmaxf(a3 + sb1a[4*q + 3], 0.0f);

    float p[F1];
#pragma unroll
    for (int j = 0; j < F1; j++)
        p[j] = u0 * sW1b[(4*q + 0) * F1 + j] + u1 * sW1b[(4*q + 1) * F1 + j]
             + u2 * sW1b[(4*q + 2) * F1 + j] + u3 * sW1b[(4*q + 3) * F1 + j];
#pragma unroll
    for (int j = 0; j < F1; j++) {                // reduce across the 4-lane group
        p[j] += __shfl_xor(p[j], 1);
        p[j] += __shfl_xor(p[j], 2);
    }
    float h[F1];
#pragma unroll
    for (int j = 0; j < F1; j++) h[j] = fmaxf(p[j] + sb1b[j], 0.0f); // relu∘relu

    int j0 = 2 * q;                               // lane writes outputs 2q, 2q+1
    float o0 = 0.0f, o1 = 0.0f;
#pragma unroll
    for (int k = 0; k < F1; k++) {
        o0 += h[k] * sW2a[k * F2 + j0];
        o1 += h[k] * sW2a[k * F2 + j0 + 1];
    }
    reinterpret_cast<float2*>(h1w)[n * 4 + q] = make_float2(o0, o1); // coalesced
}

// ==== kernel 4: layer-2 gather, 2 LANES PER NODE (1 32B req/edge) + pool ====
__global__ __launch_bounds__(256) void gin2pool_k(
    const float* __restrict__ h1w, const int* __restrict__ np_g,
    const int* __restrict__ srcs, const float* __restrict__ b2a,
    const float* __restrict__ W2b, const float* __restrict__ b2b,
    const int* __restrict__ batch, float* __restrict__ gsum,
    float* __restrict__ gcnt) {
    __shared__ float sW2b[F2 * F2];
    __shared__ float sb2a[F2];
    __shared__ float sb2b[F2];
    __shared__ float ls[NGRAPH * F2];   // 512 > blockDim -> strided loops (r5 lesson)
    __shared__ float lc[NGRAPH];
    int t = threadIdx.x;
    if (t < F2 * F2) sW2b[t] = W2b[t];
    if (t < F2) { sb2a[t] = b2a[t]; sb2b[t] = b2b[t]; }
    for (int i = t; i < NGRAPH * F2; i += 256) ls[i] = 0.0f;
    if (t < NGRAPH) lc[t] = 0.0f;
    __syncthreads();

    int hq = t & 1, slot = t >> 1;                // 128 nodes per block
    int n = blockIdx.x * 128 + slot;
    if (n < N_NODES) {
        int b = n >> BSH, sl = n & (BSZ - 1);
        int pb = b * CAPB;
        int e  = pb + np_g[b * NPW + sl];
        int e1 = pb + np_g[b * NPW + sl + 1];

        const float4* H = reinterpret_cast<const float4*>(h1w);
        float a0 = 0.0f, a1 = 0.0f, a2 = 0.0f, a3 = 0.0f;
        for (; e + 4 <= e1; e += 4) {
            int s0 = srcs[e], s1 = srcs[e+1], s2 = srcs[e+2], s3 = srcs[e+3];
            float4 v0 = H[s0 * 2 + hq];
            float4 v1 = H[s1 * 2 + hq];
            float4 v2 = H[s2 * 2 + hq];
            float4 v3 = H[s3 * 2 + hq];
            a0 += v0.x + v1.x + v2.x + v3.x;
            a1 += v0.y + v1.y + v2.y + v3.y;
            a2 += v0.z + v1.z + v2.z + v3.z;
            a3 += v0.w + v1.w + v2.w + v3.w;
        }
        for (; e < e1; e++) {
            float4 v = H[srcs[e] * 2 + hq];
            a0 += v.x; a1 += v.y; a2 += v.z; a3 += v.w;
        }
        { float4 v = H[n * 2 + hq]; a0 += v.x; a1 += v.y; a2 += v.z; a3 += v.w; }

        float u0 = fmaxf(a0 + sb2a[4*hq + 0], 0.0f);
        float u1 = fmaxf(a1 + sb2a[4*hq + 1], 0.0f);
        float u2 = fmaxf(a2 + sb2a[4*hq + 2], 0.0f);
        float u3 = fmaxf(a3 + sb2a[4*hq + 3], 0.0f);

        float p[F2];
#pragma unroll
        for (int j = 0; j < F2; j++)
            p[j] = u0 * sW2b[(4*hq + 0) * F2 + j] + u1 * sW2b[(4*hq + 1) * F2 + j]
                 + u2 * sW2b[(4*hq + 2) * F2 + j] + u3 * sW2b[(4*hq + 3) * F2 + j];
#pragma unroll
        for (int j = 0; j < F2; j++) p[j] += __shfl_xor(p[j], 1);

        int g = batch[n];
#pragma unroll
        for (int jj = 0; jj < 4; jj++) {          // lane hq flushes feats 4hq..4hq+3
            int j = 4 * hq + jj;
            float v = fmaxf(p[j] + sb2b[j], 0.0f);
            atomicAdd(&ls[g * F2 + j], v);
        }
        if (hq == 0) atomicAdd(&lc[g], 1.0f);
    }
    __syncthreads();
    for (int i = t; i < NGRAPH * F2; i += 256)
        if (ls[i] != 0.0f) atomicAdd(&gsum[i], ls[i]);
    if (t < NGRAPH && lc[t] != 0.0f) atomicAdd(&gcnt[t], lc[t]);
}

// ---------------- final: pooled -> FC -> log_softmax ----------------
__global__ void final_k(const float* __restrict__ gsum,
                        const float* __restrict__ gcnt,
                        const float* __restrict__ Wfc, const float* __restrict__ bfc,
                        float* __restrict__ out) {
    int g = threadIdx.x;
    if (g >= NGRAPH) return;
    float cnt = fmaxf(gcnt[g], 1.0f);
    float p[F2];
#pragma unroll
    for (int f = 0; f < F2; f++) p[f] = gsum[g * F2 + f] / cnt;
    float l[NCLS];
#pragma unroll
    for (int c = 0; c < NCLS; c++) {
        float s = bfc[c];
#pragma unroll
        for (int f = 0; f < F2; f++) s += p[f] * Wfc[f * NCLS + c];
        l[c] = s;
    }
    float m = -INFINITY;
#pragma unroll
    for (int c = 0; c < NCLS; c++) m = fmaxf(m, l[c]);
    float s = 0.0f;
#pragma unroll
    for (int c = 0; c < NCLS; c++) s += expf(l[c] - m);
    float lse = m + logf(s);
#pragma unroll
    for (int c = 0; c < NCLS; c++) out[g * NCLS + c] = l[c] - lse;
}

extern "C" void kernel_launch(void* const* d_in, const int* in_sizes, int n_in,
                              void* d_out, int out_size, void* d_ws, size_t ws_size,
                              hipStream_t stream) {
    const float* x    = (const float*)d_in[0];
    const int*   ei   = (const int*)d_in[1];   // [2, N_EDGES]
    const int*   batch= (const int*)d_in[2];   // [N_NODES], sorted
    const float* W1a  = (const float*)d_in[3];
    const float* b1a  = (const float*)d_in[4];
    const float* W1b  = (const float*)d_in[5];
    const float* b1b  = (const float*)d_in[6];
    const float* W2a  = (const float*)d_in[7];
    const float* b2a  = (const float*)d_in[8];
    const float* W2b  = (const float*)d_in[9];
    const float* b2b  = (const float*)d_in[10];
    const float* Wfc  = (const float*)d_in[11];
    const float* bfc  = (const float*)d_in[12];
    float* out = (float*)d_out;

    // workspace layout (4-byte units), ~24 MB
    float* ws      = (float*)d_ws;
    float* xw1     = ws;                                   // N_NODES*16
    float* h1w     = xw1 + (size_t)N_NODES * F1;           // N_NODES*8
    int*   pairs   = (int*)(h1w + (size_t)N_NODES * F2);   // NBUK*CAPB = 1801728
    int*   srcs    = pairs + (size_t)NBUK * CAPB;          // NBUK*CAPB
    int*   np_g    = srcs + (size_t)NBUK * CAPB;           // NBUK*NPW = 100487
    int*   gcursor = np_g + (size_t)NBUK * NPW + 9;        // 512   (memset)
    float* gsum    = (float*)(gcursor + 512);              // 512   (memset)
    float* gcnt    = gsum + NGRAPH * F2;                   // 64    (memset)

    // one tiny memset: gcursor + gsum + gcnt adjacent
    hipMemsetAsync(gcursor, 0, (512 + NGRAPH * F2 + NGRAPH) * sizeof(int), stream);

    xpart_k<<<NBUK, 256, 0, stream>>>(x, W1a, xw1, ei, gcursor, pairs);
    passB_k<<<NBUK, 256, 0, stream>>>(pairs, gcursor, srcs, np_g);
    gin1_k<<<(N_NODES + 63) / 64, 256, 0, stream>>>(xw1, np_g, srcs,
                                                    b1a, W1b, b1b, W2a, h1w);
    gin2pool_k<<<(N_NODES + 127) / 128, 256, 0, stream>>>(h1w, np_g, srcs,
                                                          b2a, W2b, b2b, batch,
                                                          gsum, gcnt);
    final_k<<<1, 64, 0, stream>>>(gsum, gcnt, Wfc, bfc, out);
}

// Round 14
// 170.364 us; speedup vs baseline: 1.0674x; 1.0538x over previous
//
#include <hip/hip_runtime.h>
#include <hip/hip_fp16.h>
#include <math.h>

#define N_NODES 100000
#define N_EDGES 1600000
#define F0 32
#define F1 16
#define F2 8
#define NCLS 6
#define NGRAPH 64

#define BSH  8         // bucket = 256 nodes (power of 2 -> exact split)
#define BSZ  256       // nodes per bucket
#define NBUK 391       // ceil(100000/256)
#define CAPB 4608      // edge cap per bucket region (mean 4092, sigma 64 -> +8 sigma)
#define EPB  4093      // edges per xpart chunk: ceil(1600000/391)
#define NPW  257       // np_g stride per bucket

// unpack 8 fp16 (uint4) into 8 float accumulators
__device__ __forceinline__ void acc8h(float* acc, uint4 v) {
    const __half2* p = reinterpret_cast<const __half2*>(&v);
#pragma unroll
    for (int q = 0; q < 4; q++) {
        float2 f = __half22float2(p[q]);
        acc[2*q]   += f.x;
        acc[2*q+1] += f.y;
    }
}
// unpack 4 fp16 (uint2) into 4 float accumulators
__device__ __forceinline__ void acc4h(float* acc, uint2 v) {
    const __half2* p = reinterpret_cast<const __half2*>(&v);
#pragma unroll
    for (int q = 0; q < 2; q++) {
        float2 f = __half22float2(p[q]);
        acc[2*q]   += f.x;
        acc[2*q+1] += f.y;
    }
}

// ====== kernel 1: node-transform (x@W1a -> fp16 xw1h) + edge partition ======
// fp16 xw1h = 3.2 MB -> FITS per-XCD L2 (4 MiB): layer-1 gathers become L2-hits
__global__ __launch_bounds__(256) void xpart_k(
    const float* __restrict__ x, const float* __restrict__ W1a,
    uint4* __restrict__ xw1h, const int* __restrict__ ei,
    int* __restrict__ gcursor, int* __restrict__ pairs) {
    __shared__ float sW[F0 * F1];
    __shared__ int hist[512];
    __shared__ int cur[512];
    int t = threadIdx.x, c = blockIdx.x;
    for (int i = t; i < F0 * F1; i += 256) sW[i] = W1a[i];
    hist[t] = 0; hist[t + 256] = 0;
    __syncthreads();

    // --- chunk dst histogram (streaming; chunk stays L2-hot for pass 2) ---
    int base = c * EPB, eend = min(base + EPB, N_EDGES);
    for (int i = base + t; i < eend; i += 256)
        atomicAdd(&hist[ei[N_EDGES + i] >> BSH], 1);

    // --- node projection (independent work, overlaps hist latency) ---
    int n = c * 256 + t;
    if (n < N_NODES) {
        const float4* xp = reinterpret_cast<const float4*>(x) + n * (F0 / 4);
        float xi[F0];
#pragma unroll
        for (int q = 0; q < F0 / 4; q++) {
            float4 v = xp[q];
            xi[4*q] = v.x; xi[4*q+1] = v.y; xi[4*q+2] = v.z; xi[4*q+3] = v.w;
        }
        float o[F1];
#pragma unroll
        for (int j = 0; j < F1; j++) {
            float s = 0.0f;
#pragma unroll
            for (int k = 0; k < F0; k++) s += xi[k] * sW[k * F1 + j];
            o[j] = s;
        }
        union { __half2 h2[8]; uint4 u4[2]; } pk;
#pragma unroll
        for (int j = 0; j < 8; j++)
            pk.h2[j] = __float22half2_rn(make_float2(o[2*j], o[2*j + 1]));
        xw1h[n * 2 + 0] = pk.u4[0];
        xw1h[n * 2 + 1] = pk.u4[1];
    }
    __syncthreads();

    // --- reserve contiguous sub-range per bucket (strided: NBUK > 256) ---
    for (int b = t; b < 512; b += 256) {
        int cnt = (b < NBUK) ? hist[b] : 0;
        cur[b] = b * CAPB + (cnt ? atomicAdd(&gcursor[b], cnt) : 0);
    }
    __syncthreads();

    // --- scatter packed (dl<<17 | src) into bucket regions (guarded) ---
    for (int i = base + t; i < eend; i += 256) {
        int s = ei[i];
        int d = ei[N_EDGES + i];                  // L2-hot re-read
        int b = d >> BSH;
        int pos = atomicAdd(&cur[b], 1);
        if (pos < (b + 1) * CAPB)                 // overflow guard (~never taken)
            pairs[pos] = ((d & (BSZ - 1)) << 17) | s;
    }
}

// ======= kernel 2: lean per-bucket counting sort -> srcs + np_g =======
__global__ __launch_bounds__(256) void passB_k(
    const int* __restrict__ pairs, const int* __restrict__ gcursor,
    int* __restrict__ srcs, int* __restrict__ np_g) {
    __shared__ int hist[256];
    __shared__ int sbuf[2][256];
    __shared__ int cur[256];
    int t = threadIdx.x, b = blockIdx.x;
    hist[t] = 0;
    __syncthreads();

    int cnt = min(gcursor[b], CAPB);
    int pb = b * CAPB;
    for (int i = t; i < cnt; i += 256)
        atomicAdd(&hist[pairs[pb + i] >> 17], 1);
    __syncthreads();
    sbuf[0][t] = hist[t];
    __syncthreads();
    int cb = 0;
    for (int off = 1; off < 256; off <<= 1) {
        int v = sbuf[cb][t];
        if (t >= off) v += sbuf[cb][t - off];
        sbuf[cb ^ 1][t] = v;
        cb ^= 1;
        __syncthreads();
    }
    int excl = sbuf[cb][t] - hist[t];
    cur[t] = excl;
    np_g[b * NPW + t] = excl;
    if (t == 0) np_g[b * NPW + BSZ] = cnt;
    __syncthreads();
    for (int i = t; i < cnt; i += 256) {
        int p = pairs[pb + i];
        int pos = atomicAdd(&cur[p >> 17], 1);
        srcs[pb + pos] = p & 0x1FFFF;             // bucket-local 4B writes
    }
}

// ===== kernel 3: layer-1 gather fp16 (2 lanes/node, 16B/lane) + MLP1 + W2a =====
__global__ __launch_bounds__(256) void gin1_k(
    const uint4* __restrict__ xw1h, const int* __restrict__ np_g,
    const int* __restrict__ srcs, const float* __restrict__ b1a,
    const float* __restrict__ W1b, const float* __restrict__ b1b,
    const float* __restrict__ W2a, uint2* __restrict__ h1wh) {
    __shared__ float sW1b[F1 * F1];
    __shared__ float sW2a[F1 * F2];
    __shared__ float sb1a[F1], sb1b[F1];
    int t = threadIdx.x;
    if (t < F1 * F1) sW1b[t] = W1b[t];
    if (t < F1 * F2) sW2a[t] = W2a[t];
    if (t < F1) { sb1a[t] = b1a[t]; sb1b[t] = b1b[t]; }
    __syncthreads();

    int h = t & 1, slot = t >> 1;                 // 128 nodes per block
    int n = blockIdx.x * 128 + slot;
    if (n >= N_NODES) return;
    int b = n >> BSH, sl = n & (BSZ - 1);
    int pb = b * CAPB;
    int e  = pb + np_g[b * NPW + sl];
    int e1 = pb + np_g[b * NPW + sl + 1];

    float acc[8];
#pragma unroll
    for (int k = 0; k < 8; k++) acc[k] = 0.0f;
    for (; e + 4 <= e1; e += 4) {                 // 4 rows in flight
        int s0 = srcs[e], s1 = srcs[e+1], s2 = srcs[e+2], s3 = srcs[e+3];
        uint4 v0 = xw1h[s0 * 2 + h];
        uint4 v1 = xw1h[s1 * 2 + h];
        uint4 v2 = xw1h[s2 * 2 + h];
        uint4 v3 = xw1h[s3 * 2 + h];
        acc8h(acc, v0); acc8h(acc, v1); acc8h(acc, v2); acc8h(acc, v3);
    }
    for (; e < e1; e++) acc8h(acc, xw1h[srcs[e] * 2 + h]);
    acc8h(acc, xw1h[n * 2 + h]);                  // self term

    float u[8];
#pragma unroll
    for (int k = 0; k < 8; k++) u[k] = fmaxf(acc[k] + sb1a[8*h + k], 0.0f);

    float p[F1];
#pragma unroll
    for (int j = 0; j < F1; j++) {
        float s = 0.0f;
#pragma unroll
        for (int k = 0; k < 8; k++) s += u[k] * sW1b[(8*h + k) * F1 + j];
        p[j] = s;
    }
#pragma unroll
    for (int j = 0; j < F1; j++) p[j] += __shfl_xor(p[j], 1);   // pair-combine
    float hh[F1];
#pragma unroll
    for (int j = 0; j < F1; j++) hh[j] = fmaxf(p[j] + sb1b[j], 0.0f); // relu∘relu

    float o[4];                                   // lane h owns outputs 4h..4h+3
#pragma unroll
    for (int jj = 0; jj < 4; jj++) {
        int j = 4*h + jj;
        float s = 0.0f;
#pragma unroll
        for (int k = 0; k < F1; k++) s += hh[k] * sW2a[k * F2 + j];
        o[jj] = s;
    }
    union { __half2 h2[2]; uint2 u2; } pk;
    pk.h2[0] = __float22half2_rn(make_float2(o[0], o[1]));
    pk.h2[1] = __float22half2_rn(make_float2(o[2], o[3]));
    h1wh[n * 2 + h] = pk.u2;                      // 8B/lane, pair-coalesced
}

// ==== kernel 4: layer-2 gather fp16 (2 lanes/node, 8B/lane) + MLP2 + pool ====
__global__ __launch_bounds__(256) void gin2pool_k(
    const uint2* __restrict__ h1wh, const int* __restrict__ np_g,
    const int* __restrict__ srcs, const float* __restrict__ b2a,
    const float* __restrict__ W2b, const float* __restrict__ b2b,
    const int* __restrict__ batch, float* __restrict__ gsum,
    float* __restrict__ gcnt) {
    __shared__ float sW2b[F2 * F2];
    __shared__ float sb2a[F2];
    __shared__ float sb2b[F2];
    __shared__ float ls[NGRAPH * F2];   // 512 > blockDim -> strided loops (r5 lesson)
    __shared__ float lc[NGRAPH];
    int t = threadIdx.x;
    if (t < F2 * F2) sW2b[t] = W2b[t];
    if (t < F2) { sb2a[t] = b2a[t]; sb2b[t] = b2b[t]; }
    for (int i = t; i < NGRAPH * F2; i += 256) ls[i] = 0.0f;
    if (t < NGRAPH) lc[t] = 0.0f;
    __syncthreads();

    int h = t & 1, slot = t >> 1;                 // 128 nodes per block
    int n = blockIdx.x * 128 + slot;
    if (n < N_NODES) {
        int b = n >> BSH, sl = n & (BSZ - 1);
        int pb = b * CAPB;
        int e  = pb + np_g[b * NPW + sl];
        int e1 = pb + np_g[b * NPW + sl + 1];

        float acc[4];
#pragma unroll
        for (int k = 0; k < 4; k++) acc[k] = 0.0f;
        for (; e + 4 <= e1; e += 4) {
            int s0 = srcs[e], s1 = srcs[e+1], s2 = srcs[e+2], s3 = srcs[e+3];
            uint2 v0 = h1wh[s0 * 2 + h];
            uint2 v1 = h1wh[s1 * 2 + h];
            uint2 v2 = h1wh[s2 * 2 + h];
            uint2 v3 = h1wh[s3 * 2 + h];
            acc4h(acc, v0); acc4h(acc, v1); acc4h(acc, v2); acc4h(acc, v3);
        }
        for (; e < e1; e++) acc4h(acc, h1wh[srcs[e] * 2 + h]);
        acc4h(acc, h1wh[n * 2 + h]);              // self term

        float u[4];
#pragma unroll
        for (int k = 0; k < 4; k++) u[k] = fmaxf(acc[k] + sb2a[4*h + k], 0.0f);

        float p[F2];
#pragma unroll
        for (int j = 0; j < F2; j++) {
            float s = 0.0f;
#pragma unroll
            for (int k = 0; k < 4; k++) s += u[k] * sW2b[(4*h + k) * F2 + j];
            p[j] = s;
        }
#pragma unroll
        for (int j = 0; j < F2; j++) p[j] += __shfl_xor(p[j], 1);

        int g = batch[n];
#pragma unroll
        for (int jj = 0; jj < 4; jj++) {          // lane h flushes feats 4h..4h+3
            int j = 4*h + jj;
            float v = fmaxf(p[j] + sb2b[j], 0.0f);
            atomicAdd(&ls[g * F2 + j], v);
        }
        if (h == 0) atomicAdd(&lc[g], 1.0f);
    }
    __syncthreads();
    for (int i = t; i < NGRAPH * F2; i += 256)
        if (ls[i] != 0.0f) atomicAdd(&gsum[i], ls[i]);
    if (t < NGRAPH && lc[t] != 0.0f) atomicAdd(&gcnt[t], lc[t]);
}

// ---------------- final: pooled -> FC -> log_softmax ----------------
__global__ void final_k(const float* __restrict__ gsum,
                        const float* __restrict__ gcnt,
                        const float* __restrict__ Wfc, const float* __restrict__ bfc,
                        float* __restrict__ out) {
    int g = threadIdx.x;
    if (g >= NGRAPH) return;
    float cnt = fmaxf(gcnt[g], 1.0f);
    float p[F2];
#pragma unroll
    for (int f = 0; f < F2; f++) p[f] = gsum[g * F2 + f] / cnt;
    float l[NCLS];
#pragma unroll
    for (int c = 0; c < NCLS; c++) {
        float s = bfc[c];
#pragma unroll
        for (int f = 0; f < F2; f++) s += p[f] * Wfc[f * NCLS + c];
        l[c] = s;
    }
    float m = -INFINITY;
#pragma unroll
    for (int c = 0; c < NCLS; c++) m = fmaxf(m, l[c]);
    float s = 0.0f;
#pragma unroll
    for (int c = 0; c < NCLS; c++) s += expf(l[c] - m);
    float lse = m + logf(s);
#pragma unroll
    for (int c = 0; c < NCLS; c++) out[g * NCLS + c] = l[c] - lse;
}

extern "C" void kernel_launch(void* const* d_in, const int* in_sizes, int n_in,
                              void* d_out, int out_size, void* d_ws, size_t ws_size,
                              hipStream_t stream) {
    const float* x    = (const float*)d_in[0];
    const int*   ei   = (const int*)d_in[1];   // [2, N_EDGES]
    const int*   batch= (const int*)d_in[2];   // [N_NODES], sorted
    const float* W1a  = (const float*)d_in[3];
    const float* b1a  = (const float*)d_in[4];
    const float* W1b  = (const float*)d_in[5];
    const float* b1b  = (const float*)d_in[6];
    const float* W2a  = (const float*)d_in[7];
    const float* b2a  = (const float*)d_in[8];
    const float* W2b  = (const float*)d_in[9];
    const float* b2b  = (const float*)d_in[10];
    const float* Wfc  = (const float*)d_in[11];
    const float* bfc  = (const float*)d_in[12];
    float* out = (float*)d_out;

    // workspace layout (4-byte units), ~20 MB
    float* ws      = (float*)d_ws;
    uint4* xw1h    = (uint4*)ws;                           // N_NODES*2 uint4 (fp16)
    uint2* h1wh    = (uint2*)(ws + (size_t)N_NODES * 8);   // N_NODES*2 uint2 (fp16)
    int*   pairs   = (int*)(ws + (size_t)N_NODES * 12);    // NBUK*CAPB = 1801728
    int*   srcs    = pairs + (size_t)NBUK * CAPB;          // NBUK*CAPB
    int*   np_g    = srcs + (size_t)NBUK * CAPB;           // NBUK*NPW = 100487
    int*   gcursor = np_g + (size_t)NBUK * NPW + 9;        // 512   (memset)
    float* gsum    = (float*)(gcursor + 512);              // 512   (memset)
    float* gcnt    = gsum + NGRAPH * F2;                   // 64    (memset)

    // one tiny memset: gcursor + gsum + gcnt adjacent
    hipMemsetAsync(gcursor, 0, (512 + NGRAPH * F2 + NGRAPH) * sizeof(int), stream);

    xpart_k<<<NBUK, 256, 0, stream>>>(x, W1a, xw1h, ei, gcursor, pairs);
    passB_k<<<NBUK, 256, 0, stream>>>(pairs, gcursor, srcs, np_g);
    gin1_k<<<(N_NODES + 127) / 128, 256, 0, stream>>>(xw1h, np_g, srcs,
                                                      b1a, W1b, b1b, W2a, h1wh);
    gin2pool_k<<<(N_NODES + 127) / 128, 256, 0, stream>>>(h1wh, np_g, srcs,
                                                          b2a, W2b, b2b, batch,
                                                          gsum, gcnt);
    final_k<<<1, 64, 0, stream>>>(gsum, gcnt, Wfc, bfc, out);
}

// Round 15
// 161.019 us; speedup vs baseline: 1.1294x; 1.0580x over previous
//
#include <hip/hip_runtime.h>
#include <hip/hip_fp16.h>
#include <math.h>

#define N_NODES 100000
#define N_EDGES 1600000
#define F0 32
#define F1 16
#define F2 8
#define NCLS 6
#define NGRAPH 64

#define BSH  8         // bucket = 256 nodes (power of 2 -> exact split)
#define BSZ  256       // nodes per bucket
#define NBUK 391       // ceil(100000/256)
#define CAPB 4608      // edge cap per bucket region (mean 4092, sigma 64 -> +8 sigma)
#define EPB  4093      // edges per xpart chunk: ceil(1600000/391)
#define EIT  16        // xpart dst-stage iterations: 16*256 = 4096 >= EPB
#define NPW  257       // np_g stride per bucket

// unpack 8 fp16 (uint4) into 8 float accumulators
__device__ __forceinline__ void acc8h(float* acc, uint4 v) {
    const __half2* p = reinterpret_cast<const __half2*>(&v);
#pragma unroll
    for (int q = 0; q < 4; q++) {
        float2 f = __half22float2(p[q]);
        acc[2*q]   += f.x;
        acc[2*q+1] += f.y;
    }
}
// unpack 4 fp16 (uint2) into 4 float accumulators
__device__ __forceinline__ void acc4h(float* acc, uint2 v) {
    const __half2* p = reinterpret_cast<const __half2*>(&v);
#pragma unroll
    for (int q = 0; q < 2; q++) {
        float2 f = __half22float2(p[q]);
        acc[2*q]   += f.x;
        acc[2*q+1] += f.y;
    }
}

// ====== kernel 1: node-transform (x@W1a -> fp16 xw1h) + edge partition ======
// dst values register-staged (16/thread) -> ei[dst] read exactly once.
__global__ __launch_bounds__(256) void xpart_k(
    const float* __restrict__ x, const float* __restrict__ W1a,
    uint4* __restrict__ xw1h, const int* __restrict__ ei,
    int* __restrict__ gcursor, int* __restrict__ pairs) {
    __shared__ float sW[F0 * F1];
    __shared__ int hist[512];
    __shared__ int cur[512];
    int t = threadIdx.x, c = blockIdx.x;
    for (int i = t; i < F0 * F1; i += 256) sW[i] = W1a[i];
    hist[t] = 0; hist[t + 256] = 0;
    __syncthreads();

    // --- stage dst in registers + chunk histogram ---
    int base = c * EPB, eend = min(base + EPB, N_EDGES);
    int dreg[EIT];
#pragma unroll
    for (int it = 0; it < EIT; it++) {
        int i = base + it * 256 + t;
        dreg[it] = -1;
        if (it * 256 + t < EPB && i < N_EDGES) {
            int d = ei[N_EDGES + i];
            dreg[it] = d;
            atomicAdd(&hist[d >> BSH], 1);
        }
    }

    // --- node projection (independent work, overlaps hist latency) ---
    int n = c * 256 + t;
    if (n < N_NODES) {
        const float4* xp = reinterpret_cast<const float4*>(x) + n * (F0 / 4);
        float xi[F0];
#pragma unroll
        for (int q = 0; q < F0 / 4; q++) {
            float4 v = xp[q];
            xi[4*q] = v.x; xi[4*q+1] = v.y; xi[4*q+2] = v.z; xi[4*q+3] = v.w;
        }
        float o[F1];
#pragma unroll
        for (int j = 0; j < F1; j++) {
            float s = 0.0f;
#pragma unroll
            for (int k = 0; k < F0; k++) s += xi[k] * sW[k * F1 + j];
            o[j] = s;
        }
        union { __half2 h2[8]; uint4 u4[2]; } pk;
#pragma unroll
        for (int j = 0; j < 8; j++)
            pk.h2[j] = __float22half2_rn(make_float2(o[2*j], o[2*j + 1]));
        xw1h[n * 2 + 0] = pk.u4[0];
        xw1h[n * 2 + 1] = pk.u4[1];
    }
    __syncthreads();

    // --- reserve contiguous sub-range per bucket (strided: NBUK > 256) ---
    for (int b = t; b < 512; b += 256) {
        int cnt = (b < NBUK) ? hist[b] : 0;
        cur[b] = b * CAPB + (cnt ? atomicAdd(&gcursor[b], cnt) : 0);
    }
    __syncthreads();

    // --- scatter packed (dl<<17 | src) into bucket regions (guarded) ---
#pragma unroll
    for (int it = 0; it < EIT; it++) {
        int d = dreg[it];
        if (d >= 0) {
            int i = base + it * 256 + t;
            int s = ei[i];                        // sequential src read
            int b = d >> BSH;
            int pos = atomicAdd(&cur[b], 1);
            if (pos < (b + 1) * CAPB)             // overflow guard (~never taken)
                pairs[pos] = ((d & (BSZ - 1)) << 17) | s;
        }
    }
}

// ==== kernel 2: per-bucket counting sort (LDS) + layer-1 gather from LDS ====
// 512 threads. Sort deposits srcs_l in LDS; gin1 gathers from it (no global
// round-trip for layer 1); srcs persisted once for gin2. fp16 rows, 2 lanes/node.
__global__ __launch_bounds__(512) void sortgin1_k(
    const uint4* __restrict__ xw1h, const int* __restrict__ pairs,
    const int* __restrict__ gcursor,
    const float* __restrict__ b1a, const float* __restrict__ W1b,
    const float* __restrict__ b1b, const float* __restrict__ W2a,
    uint2* __restrict__ h1wh, int* __restrict__ srcs,
    int* __restrict__ np_g) {
    __shared__ int hist[256];
    __shared__ int sbuf[2][256];
    __shared__ int cur[256];
    __shared__ int np[BSZ + 1];
    __shared__ int srcs_l[CAPB];
    __shared__ float sW1b[F1 * F1];
    __shared__ float sW2a[F1 * F2];
    __shared__ float sb1a[F1], sb1b[F1];
    int t = threadIdx.x, b = blockIdx.x;
    if (t < F1 * F1) sW1b[t] = W1b[t];
    if (t < F1 * F2) sW2a[t] = W2a[t];
    if (t < F1) { sb1a[t] = b1a[t]; sb1b[t] = b1b[t]; }
    if (t < 256) hist[t] = 0;
    __syncthreads();

    int cnt = min(gcursor[b], CAPB);
    int pb = b * CAPB;
    // hist + stage packed pairs into LDS (single global read of pairs)
    for (int i = t; i < cnt; i += 512) {
        int p = pairs[pb + i];
        srcs_l[i] = p;                            // temp: packed value
        atomicAdd(&hist[p >> 17], 1);
    }
    __syncthreads();
    if (t < 256) sbuf[0][t] = hist[t];
    __syncthreads();
    int cb = 0;
    for (int off = 1; off < 256; off <<= 1) {
        if (t < 256) {
            int v = sbuf[cb][t];
            if (t >= off) v += sbuf[cb][t - off];
            sbuf[cb ^ 1][t] = v;
        }
        cb ^= 1;
        __syncthreads();
    }
    if (t < 256) {
        int excl = sbuf[cb][t] - hist[t];
        np[t] = excl;
        cur[t] = excl;
        np_g[b * NPW + t] = excl;
        if (t == 0) { np[BSZ] = cnt; np_g[b * NPW + BSZ] = cnt; }
    }
    __syncthreads();
    // in-LDS permute would race (read/write same buffer); scatter via registers:
    // each thread holds its staged packed values, writes sorted into srcs_l.
    int myp[CAPB / 512 + 1];
    int nmy = 0;
    for (int i = t; i < cnt; i += 512) myp[nmy++] = srcs_l[i];
    __syncthreads();                              // all reads done before overwrite
    for (int k = 0; k < nmy; k++) {
        int p = myp[k];
        int pos = atomicAdd(&cur[p >> 17], 1);
        int s = p & 0x1FFFF;
        srcs_l[pos] = s;                          // sorted, consumed below
        srcs[pb + pos] = s;                       // persisted for gin2
    }
    __syncthreads();

    // ---- layer-1 gather: 2 lanes/node, 16B/lane, rows L2-resident fp16 ----
    int h = t & 1, slot = t >> 1;
    int n = b * BSZ + slot;
    if (n >= N_NODES) return;
    int e  = np[slot];
    int e1 = np[slot + 1];

    float acc[8];
#pragma unroll
    for (int k = 0; k < 8; k++) acc[k] = 0.0f;
    for (; e + 4 <= e1; e += 4) {                 // 4 rows in flight
        int s0 = srcs_l[e], s1 = srcs_l[e+1], s2 = srcs_l[e+2], s3 = srcs_l[e+3];
        uint4 v0 = xw1h[s0 * 2 + h];
        uint4 v1 = xw1h[s1 * 2 + h];
        uint4 v2 = xw1h[s2 * 2 + h];
        uint4 v3 = xw1h[s3 * 2 + h];
        acc8h(acc, v0); acc8h(acc, v1); acc8h(acc, v2); acc8h(acc, v3);
    }
    for (; e < e1; e++) acc8h(acc, xw1h[srcs_l[e] * 2 + h]);
    acc8h(acc, xw1h[n * 2 + h]);                  // self term

    float u[8];
#pragma unroll
    for (int k = 0; k < 8; k++) u[k] = fmaxf(acc[k] + sb1a[8*h + k], 0.0f);

    float p[F1];
#pragma unroll
    for (int j = 0; j < F1; j++) {
        float s = 0.0f;
#pragma unroll
        for (int k = 0; k < 8; k++) s += u[k] * sW1b[(8*h + k) * F1 + j];
        p[j] = s;
    }
#pragma unroll
    for (int j = 0; j < F1; j++) p[j] += __shfl_xor(p[j], 1);   // pair-combine
    float hh[F1];
#pragma unroll
    for (int j = 0; j < F1; j++) hh[j] = fmaxf(p[j] + sb1b[j], 0.0f); // relu∘relu

    float o[4];                                   // lane h owns outputs 4h..4h+3
#pragma unroll
    for (int jj = 0; jj < 4; jj++) {
        int j = 4*h + jj;
        float s = 0.0f;
#pragma unroll
        for (int k = 0; k < F1; k++) s += hh[k] * sW2a[k * F2 + j];
        o[jj] = s;
    }
    union { __half2 h2[2]; uint2 u2; } pk;
    pk.h2[0] = __float22half2_rn(make_float2(o[0], o[1]));
    pk.h2[1] = __float22half2_rn(make_float2(o[2], o[3]));
    h1wh[n * 2 + h] = pk.u2;                      // 8B/lane, pair-coalesced
}

// ==== kernel 3: layer-2 gather fp16 (2 lanes/node, 8B/lane) + MLP2 + pool ====
__global__ __launch_bounds__(256) void gin2pool_k(
    const uint2* __restrict__ h1wh, const int* __restrict__ np_g,
    const int* __restrict__ srcs, const float* __restrict__ b2a,
    const float* __restrict__ W2b, const float* __restrict__ b2b,
    const int* __restrict__ batch, float* __restrict__ gsum,
    float* __restrict__ gcnt) {
    __shared__ float sW2b[F2 * F2];
    __shared__ float sb2a[F2];
    __shared__ float sb2b[F2];
    __shared__ float ls[NGRAPH * F2];   // 512 > blockDim -> strided loops (r5 lesson)
    __shared__ float lc[NGRAPH];
    int t = threadIdx.x;
    if (t < F2 * F2) sW2b[t] = W2b[t];
    if (t < F2) { sb2a[t] = b2a[t]; sb2b[t] = b2b[t]; }
    for (int i = t; i < NGRAPH * F2; i += 256) ls[i] = 0.0f;
    if (t < NGRAPH) lc[t] = 0.0f;
    __syncthreads();

    int h = t & 1, slot = t >> 1;                 // 128 nodes per block
    int n = blockIdx.x * 128 + slot;
    if (n < N_NODES) {
        int b = n >> BSH, sl = n & (BSZ - 1);
        int pb = b * CAPB;
        int e  = pb + np_g[b * NPW + sl];
        int e1 = pb + np_g[b * NPW + sl + 1];

        float acc[4];
#pragma unroll
        for (int k = 0; k < 4; k++) acc[k] = 0.0f;
        for (; e + 4 <= e1; e += 4) {
            int s0 = srcs[e], s1 = srcs[e+1], s2 = srcs[e+2], s3 = srcs[e+3];
            uint2 v0 = h1wh[s0 * 2 + h];
            uint2 v1 = h1wh[s1 * 2 + h];
            uint2 v2 = h1wh[s2 * 2 + h];
            uint2 v3 = h1wh[s3 * 2 + h];
            acc4h(acc, v0); acc4h(acc, v1); acc4h(acc, v2); acc4h(acc, v3);
        }
        for (; e < e1; e++) acc4h(acc, h1wh[srcs[e] * 2 + h]);
        acc4h(acc, h1wh[n * 2 + h]);              // self term

        float u[4];
#pragma unroll
        for (int k = 0; k < 4; k++) u[k] = fmaxf(acc[k] + sb2a[4*h + k], 0.0f);

        float p[F2];
#pragma unroll
        for (int j = 0; j < F2; j++) {
            float s = 0.0f;
#pragma unroll
            for (int k = 0; k < 4; k++) s += u[k] * sW2b[(4*h + k) * F2 + j];
            p[j] = s;
        }
#pragma unroll
        for (int j = 0; j < F2; j++) p[j] += __shfl_xor(p[j], 1);

        int g = batch[n];
#pragma unroll
        for (int jj = 0; jj < 4; jj++) {          // lane h flushes feats 4h..4h+3
            int j = 4*h + jj;
            float v = fmaxf(p[j] + sb2b[j], 0.0f);
            atomicAdd(&ls[g * F2 + j], v);
        }
        if (h == 0) atomicAdd(&lc[g], 1.0f);
    }
    __syncthreads();
    for (int i = t; i < NGRAPH * F2; i += 256)
        if (ls[i] != 0.0f) atomicAdd(&gsum[i], ls[i]);
    if (t < NGRAPH && lc[t] != 0.0f) atomicAdd(&gcnt[t], lc[t]);
}

// ---------------- final: pooled -> FC -> log_softmax ----------------
__global__ void final_k(const float* __restrict__ gsum,
                        const float* __restrict__ gcnt,
                        const float* __restrict__ Wfc, const float* __restrict__ bfc,
                        float* __restrict__ out) {
    int g = threadIdx.x;
    if (g >= NGRAPH) return;
    float cnt = fmaxf(gcnt[g], 1.0f);
    float p[F2];
#pragma unroll
    for (int f = 0; f < F2; f++) p[f] = gsum[g * F2 + f] / cnt;
    float l[NCLS];
#pragma unroll
    for (int c = 0; c < NCLS; c++) {
        float s = bfc[c];
#pragma unroll
        for (int f = 0; f < F2; f++) s += p[f] * Wfc[f * NCLS + c];
        l[c] = s;
    }
    float m = -INFINITY;
#pragma unroll
    for (int c = 0; c < NCLS; c++) m = fmaxf(m, l[c]);
    float s = 0.0f;
#pragma unroll
    for (int c = 0; c < NCLS; c++) s += expf(l[c] - m);
    float lse = m + logf(s);
#pragma unroll
    for (int c = 0; c < NCLS; c++) out[g * NCLS + c] = l[c] - lse;
}

extern "C" void kernel_launch(void* const* d_in, const int* in_sizes, int n_in,
                              void* d_out, int out_size, void* d_ws, size_t ws_size,
                              hipStream_t stream) {
    const float* x    = (const float*)d_in[0];
    const int*   ei   = (const int*)d_in[1];   // [2, N_EDGES]
    const int*   batch= (const int*)d_in[2];   // [N_NODES], sorted
    const float* W1a  = (const float*)d_in[3];
    const float* b1a  = (const float*)d_in[4];
    const float* W1b  = (const float*)d_in[5];
    const float* b1b  = (const float*)d_in[6];
    const float* W2a  = (const float*)d_in[7];
    const float* b2a  = (const float*)d_in[8];
    const float* W2b  = (const float*)d_in[9];
    const float* b2b  = (const float*)d_in[10];
    const float* Wfc  = (const float*)d_in[11];
    const float* bfc  = (const float*)d_in[12];
    float* out = (float*)d_out;

    // workspace layout (4-byte units), ~20 MB
    float* ws      = (float*)d_ws;
    uint4* xw1h    = (uint4*)ws;                           // N_NODES*2 uint4 (fp16)
    uint2* h1wh    = (uint2*)(ws + (size_t)N_NODES * 8);   // N_NODES*2 uint2 (fp16)
    int*   pairs   = (int*)(ws + (size_t)N_NODES * 12);    // NBUK*CAPB = 1801728
    int*   srcs    = pairs + (size_t)NBUK * CAPB;          // NBUK*CAPB
    int*   np_g    = srcs + (size_t)NBUK * CAPB;           // NBUK*NPW = 100487
    int*   gcursor = np_g + (size_t)NBUK * NPW + 9;        // 512   (memset)
    float* gsum    = (float*)(gcursor + 512);              // 512   (memset)
    float* gcnt    = gsum + NGRAPH * F2;                   // 64    (memset)

    // one tiny memset: gcursor + gsum + gcnt adjacent
    hipMemsetAsync(gcursor, 0, (512 + NGRAPH * F2 + NGRAPH) * sizeof(int), stream);

    xpart_k<<<NBUK, 256, 0, stream>>>(x, W1a, xw1h, ei, gcursor, pairs);
    sortgin1_k<<<NBUK, 512, 0, stream>>>(xw1h, pairs, gcursor,
                                         b1a, W1b, b1b, W2a,
                                         h1wh, srcs, np_g);
    gin2pool_k<<<(N_NODES + 127) / 128, 256, 0, stream>>>(h1wh, np_g, srcs,
                                                          b2a, W2b, b2b, batch,
                                                          gsum, gcnt);
    final_k<<<1, 64, 0, stream>>>(gsum, gcnt, Wfc, bfc, out);
}

// Round 16
// 153.579 us; speedup vs baseline: 1.1841x; 1.0484x over previous
//
#include <hip/hip_runtime.h>
#include <hip/hip_fp16.h>
#include <math.h>

#define N_NODES 100000
#define N_EDGES 1600000
#define F0 32
#define F1 16
#define F2 8
#define NCLS 6
#define NGRAPH 64

#define BSH  8         // bucket = 256 nodes (power of 2 -> exact split)
#define BSZ  256       // nodes per bucket
#define NBUK 391       // ceil(100000/256)
#define CAPB 4608      // edge cap per bucket region (mean 4092, sigma 64 -> +8 sigma)
#define EPB  4093      // edges per xpart chunk: ceil(1600000/391)
#define XEIT 8         // xpart dst-stage iterations: 8*512 = 4096 >= EPB
#define NPW  257       // np_g stride per bucket

// unpack 8 fp16 (uint4) into 8 float accumulators
__device__ __forceinline__ void acc8h(float* acc, uint4 v) {
    const __half2* p = reinterpret_cast<const __half2*>(&v);
#pragma unroll
    for (int q = 0; q < 4; q++) {
        float2 f = __half22float2(p[q]);
        acc[2*q]   += f.x;
        acc[2*q+1] += f.y;
    }
}
// unpack 4 fp16 (uint2) into 4 float accumulators
__device__ __forceinline__ void acc4h(float* acc, uint2 v) {
    const __half2* p = reinterpret_cast<const __half2*>(&v);
#pragma unroll
    for (int q = 0; q < 2; q++) {
        float2 f = __half22float2(p[q]);
        acc[2*q]   += f.x;
        acc[2*q+1] += f.y;
    }
}

// ====== kernel 1: node-transform (x@W1a -> fp16) + WRITE-COALESCED partition ======
// Chunk-local LDS counting sort by bucket, THEN write out: consecutive lanes
// write consecutive addresses in each bucket's reserved run (~7 reqs/wave vs 64).
__global__ __launch_bounds__(512) void xpart_k(
    const float* __restrict__ x, const float* __restrict__ W1a,
    uint4* __restrict__ xw1h, const int* __restrict__ ei,
    int* __restrict__ gcursor, int* __restrict__ pairs) {
    __shared__ float sW[F0 * F1];
    __shared__ int hist[512];              // counts -> excl (reused)
    __shared__ int scan[512];
    __shared__ int gbase[512];
    __shared__ int lcur[512];
    __shared__ int lpk[4096];              // chunk edges, bucket-sorted (packed)
    __shared__ unsigned short lb[4096];    // bucket id per sorted edge
    int t = threadIdx.x, c = blockIdx.x;
    for (int i = t; i < F0 * F1; i += 512) sW[i] = W1a[i];
    hist[t] = 0;
    __syncthreads();

    // --- stage dst in registers + chunk histogram ---
    int base = c * EPB;
    int dreg[XEIT];
#pragma unroll
    for (int it = 0; it < XEIT; it++) {
        int li = it * 512 + t;
        int i = base + li;
        dreg[it] = -1;
        if (li < EPB && i < N_EDGES) {
            int d = ei[N_EDGES + i];
            dreg[it] = d;
            atomicAdd(&hist[d >> BSH], 1);
        }
    }

    // --- node projection (first 256 threads; independent work) ---
    if (t < 256) {
        int n = c * 256 + t;
        if (n < N_NODES) {
            const float4* xp = reinterpret_cast<const float4*>(x) + n * (F0 / 4);
            float xi[F0];
#pragma unroll
            for (int q = 0; q < F0 / 4; q++) {
                float4 v = xp[q];
                xi[4*q] = v.x; xi[4*q+1] = v.y; xi[4*q+2] = v.z; xi[4*q+3] = v.w;
            }
            float o[F1];
#pragma unroll
            for (int j = 0; j < F1; j++) {
                float s = 0.0f;
#pragma unroll
                for (int k = 0; k < F0; k++) s += xi[k] * sW[k * F1 + j];
                o[j] = s;
            }
            union { __half2 h2[8]; uint4 u4[2]; } pk;
#pragma unroll
            for (int j = 0; j < 8; j++)
                pk.h2[j] = __float22half2_rn(make_float2(o[2*j], o[2*j + 1]));
            xw1h[n * 2 + 0] = pk.u4[0];
            xw1h[n * 2 + 1] = pk.u4[1];
        }
    }
    __syncthreads();

    // --- inclusive scan of hist -> chunk-local excl + global reservation ---
    scan[t] = hist[t];
    __syncthreads();
    for (int off = 1; off < 512; off <<= 1) {
        int v = scan[t];
        if (t >= off) v += scan[t - off];
        __syncthreads();
        scan[t] = v;
        __syncthreads();
    }
    int ex = scan[t] - hist[t];
    int cntb = hist[t];
    lcur[t] = ex;
    gbase[t] = (t < NBUK) ? (t * CAPB + (cntb ? atomicAdd(&gcursor[t], cntb) : 0))
                          : 0;
    hist[t] = ex;                          // hist[] now holds excl[]
    __syncthreads();

    // --- place staged edges into LDS, sorted by bucket ---
#pragma unroll
    for (int it = 0; it < XEIT; it++) {
        int d = dreg[it];
        if (d >= 0) {
            int i = base + it * 512 + t;
            int s = ei[i];                 // sequential src read
            int b = d >> BSH;
            int slot = atomicAdd(&lcur[b], 1);
            lpk[slot] = ((d & (BSZ - 1)) << 17) | s;
            lb[slot] = (unsigned short)b;
        }
    }
    __syncthreads();

    // --- coalesced write-out: consecutive i -> consecutive addr within runs ---
    int tot = min(EPB, N_EDGES - base);
    for (int i = t; i < tot; i += 512) {
        int b = lb[i];
        int gpos = gbase[b] + (i - hist[b]);
        if (gpos < (b + 1) * CAPB)         // overflow guard (~never taken)
            pairs[gpos] = lpk[i];
    }
}

// ==== kernel 2: per-bucket counting sort (LDS) + layer-1 gather from LDS ====
__global__ __launch_bounds__(512) void sortgin1_k(
    const uint4* __restrict__ xw1h, const int* __restrict__ pairs,
    const int* __restrict__ gcursor,
    const float* __restrict__ b1a, const float* __restrict__ W1b,
    const float* __restrict__ b1b, const float* __restrict__ W2a,
    uint2* __restrict__ h1wh, int* __restrict__ srcs,
    int* __restrict__ np_g) {
    __shared__ int hist[256];
    __shared__ int sbuf[2][256];
    __shared__ int cur[256];
    __shared__ int np[BSZ + 1];
    __shared__ int srcs_l[CAPB];
    __shared__ float sW1b[F1 * F1];
    __shared__ float sW2a[F1 * F2];
    __shared__ float sb1a[F1], sb1b[F1];
    int t = threadIdx.x, b = blockIdx.x;
    if (t < F1 * F1) sW1b[t] = W1b[t];
    if (t < F1 * F2) sW2a[t] = W2a[t];
    if (t < F1) { sb1a[t] = b1a[t]; sb1b[t] = b1b[t]; }
    if (t < 256) hist[t] = 0;
    __syncthreads();

    int cnt = min(gcursor[b], CAPB);
    int pb = b * CAPB;
    // hist + stage packed pairs into LDS (single global read of pairs)
    for (int i = t; i < cnt; i += 512) {
        int p = pairs[pb + i];
        srcs_l[i] = p;                            // temp: packed value
        atomicAdd(&hist[p >> 17], 1);
    }
    __syncthreads();
    if (t < 256) sbuf[0][t] = hist[t];
    __syncthreads();
    int cb = 0;
    for (int off = 1; off < 256; off <<= 1) {
        if (t < 256) {
            int v = sbuf[cb][t];
            if (t >= off) v += sbuf[cb][t - off];
            sbuf[cb ^ 1][t] = v;
        }
        cb ^= 1;
        __syncthreads();
    }
    if (t < 256) {
        int excl = sbuf[cb][t] - hist[t];
        np[t] = excl;
        cur[t] = excl;
        np_g[b * NPW + t] = excl;
        if (t == 0) { np[BSZ] = cnt; np_g[b * NPW + BSZ] = cnt; }
    }
    __syncthreads();
    // register-stage, then scatter sorted into srcs_l (avoids in-LDS race)
    int myp[CAPB / 512 + 1];
    int nmy = 0;
    for (int i = t; i < cnt; i += 512) myp[nmy++] = srcs_l[i];
    __syncthreads();                              // all reads done before overwrite
    for (int k = 0; k < nmy; k++) {
        int p = myp[k];
        int pos = atomicAdd(&cur[p >> 17], 1);
        int s = p & 0x1FFFF;
        srcs_l[pos] = s;                          // sorted, consumed below
        srcs[pb + pos] = s;                       // persisted for gin2
    }
    __syncthreads();

    // ---- layer-1 gather: 2 lanes/node, 16B/lane, rows L2-resident fp16 ----
    int h = t & 1, slot = t >> 1;
    int n = b * BSZ + slot;
    if (n >= N_NODES) return;
    int e  = np[slot];
    int e1 = np[slot + 1];

    float acc[8];
#pragma unroll
    for (int k = 0; k < 8; k++) acc[k] = 0.0f;
    for (; e + 4 <= e1; e += 4) {                 // 4 rows in flight
        int s0 = srcs_l[e], s1 = srcs_l[e+1], s2 = srcs_l[e+2], s3 = srcs_l[e+3];
        uint4 v0 = xw1h[s0 * 2 + h];
        uint4 v1 = xw1h[s1 * 2 + h];
        uint4 v2 = xw1h[s2 * 2 + h];
        uint4 v3 = xw1h[s3 * 2 + h];
        acc8h(acc, v0); acc8h(acc, v1); acc8h(acc, v2); acc8h(acc, v3);
    }
    for (; e < e1; e++) acc8h(acc, xw1h[srcs_l[e] * 2 + h]);
    acc8h(acc, xw1h[n * 2 + h]);                  // self term

    float u[8];
#pragma unroll
    for (int k = 0; k < 8; k++) u[k] = fmaxf(acc[k] + sb1a[8*h + k], 0.0f);

    float p[F1];
#pragma unroll
    for (int j = 0; j < F1; j++) {
        float s = 0.0f;
#pragma unroll
        for (int k = 0; k < 8; k++) s += u[k] * sW1b[(8*h + k) * F1 + j];
        p[j] = s;
    }
#pragma unroll
    for (int j = 0; j < F1; j++) p[j] += __shfl_xor(p[j], 1);   // pair-combine
    float hh[F1];
#pragma unroll
    for (int j = 0; j < F1; j++) hh[j] = fmaxf(p[j] + sb1b[j], 0.0f); // relu∘relu

    float o[4];                                   // lane h owns outputs 4h..4h+3
#pragma unroll
    for (int jj = 0; jj < 4; jj++) {
        int j = 4*h + jj;
        float s = 0.0f;
#pragma unroll
        for (int k = 0; k < F1; k++) s += hh[k] * sW2a[k * F2 + j];
        o[jj] = s;
    }
    union { __half2 h2[2]; uint2 u2; } pk;
    pk.h2[0] = __float22half2_rn(make_float2(o[0], o[1]));
    pk.h2[1] = __float22half2_rn(make_float2(o[2], o[3]));
    h1wh[n * 2 + h] = pk.u2;                      // 8B/lane, pair-coalesced
}

// ==== kernel 3: layer-2 gather fp16 (2 lanes/node, 8B/lane) + MLP2 + pool ====
__global__ __launch_bounds__(256) void gin2pool_k(
    const uint2* __restrict__ h1wh, const int* __restrict__ np_g,
    const int* __restrict__ srcs, const float* __restrict__ b2a,
    const float* __restrict__ W2b, const float* __restrict__ b2b,
    const int* __restrict__ batch, float* __restrict__ gsum,
    float* __restrict__ gcnt) {
    __shared__ float sW2b[F2 * F2];
    __shared__ float sb2a[F2];
    __shared__ float sb2b[F2];
    __shared__ float ls[NGRAPH * F2];   // 512 > blockDim -> strided loops (r5 lesson)
    __shared__ float lc[NGRAPH];
    int t = threadIdx.x;
    if (t < F2 * F2) sW2b[t] = W2b[t];
    if (t < F2) { sb2a[t] = b2a[t]; sb2b[t] = b2b[t]; }
    for (int i = t; i < NGRAPH * F2; i += 256) ls[i] = 0.0f;
    if (t < NGRAPH) lc[t] = 0.0f;
    __syncthreads();

    int h = t & 1, slot = t >> 1;                 // 128 nodes per block
    int n = blockIdx.x * 128 + slot;
    if (n < N_NODES) {
        int b = n >> BSH, sl = n & (BSZ - 1);
        int pb = b * CAPB;
        int e  = pb + np_g[b * NPW + sl];
        int e1 = pb + np_g[b * NPW + sl + 1];

        float acc[4];
#pragma unroll
        for (int k = 0; k < 4; k++) acc[k] = 0.0f;
        for (; e + 4 <= e1; e += 4) {
            int s0 = srcs[e], s1 = srcs[e+1], s2 = srcs[e+2], s3 = srcs[e+3];
            uint2 v0 = h1wh[s0 * 2 + h];
            uint2 v1 = h1wh[s1 * 2 + h];
            uint2 v2 = h1wh[s2 * 2 + h];
            uint2 v3 = h1wh[s3 * 2 + h];
            acc4h(acc, v0); acc4h(acc, v1); acc4h(acc, v2); acc4h(acc, v3);
        }
        for (; e < e1; e++) acc4h(acc, h1wh[srcs[e] * 2 + h]);
        acc4h(acc, h1wh[n * 2 + h]);              // self term

        float u[4];
#pragma unroll
        for (int k = 0; k < 4; k++) u[k] = fmaxf(acc[k] + sb2a[4*h + k], 0.0f);

        float p[F2];
#pragma unroll
        for (int j = 0; j < F2; j++) {
            float s = 0.0f;
#pragma unroll
            for (int k = 0; k < 4; k++) s += u[k] * sW2b[(4*h + k) * F2 + j];
            p[j] = s;
        }
#pragma unroll
        for (int j = 0; j < F2; j++) p[j] += __shfl_xor(p[j], 1);

        int g = batch[n];
#pragma unroll
        for (int jj = 0; jj < 4; jj++) {          // lane h flushes feats 4h..4h+3
            int j = 4*h + jj;
            float v = fmaxf(p[j] + sb2b[j], 0.0f);
            atomicAdd(&ls[g * F2 + j], v);
        }
        if (h == 0) atomicAdd(&lc[g], 1.0f);
    }
    __syncthreads();
    for (int i = t; i < NGRAPH * F2; i += 256)
        if (ls[i] != 0.0f) atomicAdd(&gsum[i], ls[i]);
    if (t < NGRAPH && lc[t] != 0.0f) atomicAdd(&gcnt[t], lc[t]);
}

// ---------------- final: pooled -> FC -> log_softmax ----------------
__global__ void final_k(const float* __restrict__ gsum,
                        const float* __restrict__ gcnt,
                        const float* __restrict__ Wfc, const float* __restrict__ bfc,
                        float* __restrict__ out) {
    int g = threadIdx.x;
    if (g >= NGRAPH) return;
    float cnt = fmaxf(gcnt[g], 1.0f);
    float p[F2];
#pragma unroll
    for (int f = 0; f < F2; f++) p[f] = gsum[g * F2 + f] / cnt;
    float l[NCLS];
#pragma unroll
    for (int c = 0; c < NCLS; c++) {
        float s = bfc[c];
#pragma unroll
        for (int f = 0; f < F2; f++) s += p[f] * Wfc[f * NCLS + c];
        l[c] = s;
    }
    float m = -INFINITY;
#pragma unroll
    for (int c = 0; c < NCLS; c++) m = fmaxf(m, l[c]);
    float s = 0.0f;
#pragma unroll
    for (int c = 0; c < NCLS; c++) s += expf(l[c] - m);
    float lse = m + logf(s);
#pragma unroll
    for (int c = 0; c < NCLS; c++) out[g * NCLS + c] = l[c] - lse;
}

extern "C" void kernel_launch(void* const* d_in, const int* in_sizes, int n_in,
                              void* d_out, int out_size, void* d_ws, size_t ws_size,
                              hipStream_t stream) {
    const float* x    = (const float*)d_in[0];
    const int*   ei   = (const int*)d_in[1];   // [2, N_EDGES]
    const int*   batch= (const int*)d_in[2];   // [N_NODES], sorted
    const float* W1a  = (const float*)d_in[3];
    const float* b1a  = (const float*)d_in[4];
    const float* W1b  = (const float*)d_in[5];
    const float* b1b  = (const float*)d_in[6];
    const float* W2a  = (const float*)d_in[7];
    const float* b2a  = (const float*)d_in[8];
    const float* W2b  = (const float*)d_in[9];
    const float* b2b  = (const float*)d_in[10];
    const float* Wfc  = (const float*)d_in[11];
    const float* bfc  = (const float*)d_in[12];
    float* out = (float*)d_out;

    // workspace layout (4-byte units), ~20 MB
    float* ws      = (float*)d_ws;
    uint4* xw1h    = (uint4*)ws;                           // N_NODES*2 uint4 (fp16)
    uint2* h1wh    = (uint2*)(ws + (size_t)N_NODES * 8);   // N_NODES*2 uint2 (fp16)
    int*   pairs   = (int*)(ws + (size_t)N_NODES * 12);    // NBUK*CAPB = 1801728
    int*   srcs    = pairs + (size_t)NBUK * CAPB;          // NBUK*CAPB
    int*   np_g    = srcs + (size_t)NBUK * CAPB;           // NBUK*NPW = 100487
    int*   gcursor = np_g + (size_t)NBUK * NPW + 9;        // 512   (memset)
    float* gsum    = (float*)(gcursor + 512);              // 512   (memset)
    float* gcnt    = gsum + NGRAPH * F2;                   // 64    (memset)

    // one tiny memset: gcursor + gsum + gcnt adjacent
    hipMemsetAsync(gcursor, 0, (512 + NGRAPH * F2 + NGRAPH) * sizeof(int), stream);

    xpart_k<<<NBUK, 512, 0, stream>>>(x, W1a, xw1h, ei, gcursor, pairs);
    sortgin1_k<<<NBUK, 512, 0, stream>>>(xw1h, pairs, gcursor,
                                         b1a, W1b, b1b, W2a,
                                         h1wh, srcs, np_g);
    gin2pool_k<<<(N_NODES + 127) / 128, 256, 0, stream>>>(h1wh, np_g, srcs,
                                                          b2a, W2b, b2b, batch,
                                                          gsum, gcnt);
    final_k<<<1, 64, 0, stream>>>(gsum, gcnt, Wfc, bfc, out);
}

// Round 17
// 149.159 us; speedup vs baseline: 1.2192x; 1.0296x over previous
//
#include <hip/hip_runtime.h>
#include <hip/hip_fp16.h>
#include <math.h>

#define N_NODES 100000
#define N_EDGES 1600000
#define F0 32
#define F1 16
#define F2 8
#define NCLS 6
#define NGRAPH 64

#define BSH  8         // bucket = 256 nodes (power of 2 -> exact split)
#define BSZ  256       // nodes per bucket
#define NBUK 391       // ceil(100000/256)
#define CAPB 4608      // edge cap per bucket region (mean 4092, sigma 64 -> +8 sigma)
#define EPB  4093      // edges per xpart chunk: ceil(1600000/391)
#define XEIT 8         // xpart stage iterations: 8*512 = 4096 >= EPB
#define NPW  257       // np_g stride per bucket

// unpack 8 fp16 (uint4) into 8 float accumulators
__device__ __forceinline__ void acc8h(float* acc, uint4 v) {
    const __half2* p = reinterpret_cast<const __half2*>(&v);
#pragma unroll
    for (int q = 0; q < 4; q++) {
        float2 f = __half22float2(p[q]);
        acc[2*q]   += f.x;
        acc[2*q+1] += f.y;
    }
}
// unpack 4 fp16 (uint2) into 4 float accumulators
__device__ __forceinline__ void acc4h(float* acc, uint2 v) {
    const __half2* p = reinterpret_cast<const __half2*>(&v);
#pragma unroll
    for (int q = 0; q < 2; q++) {
        float2 f = __half22float2(p[q]);
        acc[2*q]   += f.x;
        acc[2*q+1] += f.y;
    }
}

// ====== kernel 1: node-transform (x@W1a -> fp16) + write-coalesced partition ======
// src AND dst register-staged -> all ei reads issue as one early sequential burst;
// placement loop is pure-LDS. Write-out is bucket-sorted (r15 win).
__global__ __launch_bounds__(512) void xpart_k(
    const float* __restrict__ x, const float* __restrict__ W1a,
    uint4* __restrict__ xw1h, const int* __restrict__ ei,
    int* __restrict__ gcursor, int* __restrict__ pairs) {
    __shared__ float sW[F0 * F1];
    __shared__ int hist[512];              // counts -> excl (reused)
    __shared__ int scan[512];
    __shared__ int gbase[512];
    __shared__ int lcur[512];
    __shared__ int lpk[4096];              // chunk edges, bucket-sorted (packed)
    __shared__ unsigned short lb[4096];    // bucket id per sorted edge
    int t = threadIdx.x, c = blockIdx.x;
    for (int i = t; i < F0 * F1; i += 512) sW[i] = W1a[i];
    hist[t] = 0;
    __syncthreads();

    // --- stage src+dst in registers + chunk histogram ---
    int base = c * EPB;
    int dreg[XEIT], sreg[XEIT];
#pragma unroll
    for (int it = 0; it < XEIT; it++) {
        int li = it * 512 + t;
        int i = base + li;
        dreg[it] = -1;
        if (li < EPB && i < N_EDGES) {
            sreg[it] = ei[i];
            int d = ei[N_EDGES + i];
            dreg[it] = d;
            atomicAdd(&hist[d >> BSH], 1);
        }
    }

    // --- node projection (first 256 threads; independent work) ---
    if (t < 256) {
        int n = c * 256 + t;
        if (n < N_NODES) {
            const float4* xp = reinterpret_cast<const float4*>(x) + n * (F0 / 4);
            float xi[F0];
#pragma unroll
            for (int q = 0; q < F0 / 4; q++) {
                float4 v = xp[q];
                xi[4*q] = v.x; xi[4*q+1] = v.y; xi[4*q+2] = v.z; xi[4*q+3] = v.w;
            }
            float o[F1];
#pragma unroll
            for (int j = 0; j < F1; j++) {
                float s = 0.0f;
#pragma unroll
                for (int k = 0; k < F0; k++) s += xi[k] * sW[k * F1 + j];
                o[j] = s;
            }
            union { __half2 h2[8]; uint4 u4[2]; } pk;
#pragma unroll
            for (int j = 0; j < 8; j++)
                pk.h2[j] = __float22half2_rn(make_float2(o[2*j], o[2*j + 1]));
            xw1h[n * 2 + 0] = pk.u4[0];
            xw1h[n * 2 + 1] = pk.u4[1];
        }
    }
    __syncthreads();

    // --- inclusive scan of hist -> chunk-local excl + global reservation ---
    scan[t] = hist[t];
    __syncthreads();
    for (int off = 1; off < 512; off <<= 1) {
        int v = scan[t];
        if (t >= off) v += scan[t - off];
        __syncthreads();
        scan[t] = v;
        __syncthreads();
    }
    int ex = scan[t] - hist[t];
    int cntb = hist[t];
    lcur[t] = ex;
    gbase[t] = (t < NBUK) ? (t * CAPB + (cntb ? atomicAdd(&gcursor[t], cntb) : 0))
                          : 0;
    hist[t] = ex;                          // hist[] now holds excl[]
    __syncthreads();

    // --- place staged edges into LDS, sorted by bucket (pure LDS ops) ---
#pragma unroll
    for (int it = 0; it < XEIT; it++) {
        int d = dreg[it];
        if (d >= 0) {
            int b = d >> BSH;
            int slot = atomicAdd(&lcur[b], 1);
            lpk[slot] = ((d & (BSZ - 1)) << 17) | sreg[it];
            lb[slot] = (unsigned short)b;
        }
    }
    __syncthreads();

    // --- coalesced write-out: consecutive i -> consecutive addr within runs ---
    int tot = min(EPB, N_EDGES - base);
    for (int i = t; i < tot; i += 512) {
        int b = lb[i];
        int gpos = gbase[b] + (i - hist[b]);
        if (gpos < (b + 1) * CAPB)         // overflow guard (~never taken)
            pairs[gpos] = lpk[i];
    }
}

// ==== kernel 2: per-bucket counting sort (LDS) + layer-1 gather from LDS ====
// srcs persisted via LINEAR copy of the sorted LDS buffer (coalesced; r16 change)
__global__ __launch_bounds__(512) void sortgin1_k(
    const uint4* __restrict__ xw1h, const int* __restrict__ pairs,
    const int* __restrict__ gcursor,
    const float* __restrict__ b1a, const float* __restrict__ W1b,
    const float* __restrict__ b1b, const float* __restrict__ W2a,
    uint2* __restrict__ h1wh, int* __restrict__ srcs,
    int* __restrict__ np_g) {
    __shared__ int hist[256];
    __shared__ int sbuf[2][256];
    __shared__ int cur[256];
    __shared__ int np[BSZ + 1];
    __shared__ int srcs_l[CAPB];
    __shared__ float sW1b[F1 * F1];
    __shared__ float sW2a[F1 * F2];
    __shared__ float sb1a[F1], sb1b[F1];
    int t = threadIdx.x, b = blockIdx.x;
    if (t < F1 * F1) sW1b[t] = W1b[t];
    if (t < F1 * F2) sW2a[t] = W2a[t];
    if (t < F1) { sb1a[t] = b1a[t]; sb1b[t] = b1b[t]; }
    if (t < 256) hist[t] = 0;
    __syncthreads();

    int cnt = min(gcursor[b], CAPB);
    int pb = b * CAPB;
    // hist + stage packed pairs into LDS (single global read of pairs)
    for (int i = t; i < cnt; i += 512) {
        int p = pairs[pb + i];
        srcs_l[i] = p;                            // temp: packed value
        atomicAdd(&hist[p >> 17], 1);
    }
    __syncthreads();
    if (t < 256) sbuf[0][t] = hist[t];
    __syncthreads();
    int cb = 0;
    for (int off = 1; off < 256; off <<= 1) {
        if (t < 256) {
            int v = sbuf[cb][t];
            if (t >= off) v += sbuf[cb][t - off];
            sbuf[cb ^ 1][t] = v;
        }
        cb ^= 1;
        __syncthreads();
    }
    if (t < 256) {
        int excl = sbuf[cb][t] - hist[t];
        np[t] = excl;
        cur[t] = excl;
        np_g[b * NPW + t] = excl;
        if (t == 0) { np[BSZ] = cnt; np_g[b * NPW + BSZ] = cnt; }
    }
    __syncthreads();
    // register-stage, then scatter sorted into srcs_l (avoids in-LDS race)
    int myp[CAPB / 512 + 1];
    int nmy = 0;
    for (int i = t; i < cnt; i += 512) myp[nmy++] = srcs_l[i];
    __syncthreads();                              // all reads done before overwrite
    for (int k = 0; k < nmy; k++) {
        int p = myp[k];
        int pos = atomicAdd(&cur[p >> 17], 1);
        srcs_l[pos] = p & 0x1FFFF;                // sorted, consumed below
    }
    __syncthreads();
    // coalesced persist for gin2: consecutive lanes -> consecutive addresses
    for (int i = t; i < cnt; i += 512) srcs[pb + i] = srcs_l[i];

    // ---- layer-1 gather: 2 lanes/node, 16B/lane, rows L2-resident fp16 ----
    int h = t & 1, slot = t >> 1;
    int n = b * BSZ + slot;
    if (n >= N_NODES) return;
    int e  = np[slot];
    int e1 = np[slot + 1];

    float acc[8];
#pragma unroll
    for (int k = 0; k < 8; k++) acc[k] = 0.0f;
    for (; e + 4 <= e1; e += 4) {                 // 4 rows in flight
        int s0 = srcs_l[e], s1 = srcs_l[e+1], s2 = srcs_l[e+2], s3 = srcs_l[e+3];
        uint4 v0 = xw1h[s0 * 2 + h];
        uint4 v1 = xw1h[s1 * 2 + h];
        uint4 v2 = xw1h[s2 * 2 + h];
        uint4 v3 = xw1h[s3 * 2 + h];
        acc8h(acc, v0); acc8h(acc, v1); acc8h(acc, v2); acc8h(acc, v3);
    }
    for (; e < e1; e++) acc8h(acc, xw1h[srcs_l[e] * 2 + h]);
    acc8h(acc, xw1h[n * 2 + h]);                  // self term

    float u[8];
#pragma unroll
    for (int k = 0; k < 8; k++) u[k] = fmaxf(acc[k] + sb1a[8*h + k], 0.0f);

    float p[F1];
#pragma unroll
    for (int j = 0; j < F1; j++) {
        float s = 0.0f;
#pragma unroll
        for (int k = 0; k < 8; k++) s += u[k] * sW1b[(8*h + k) * F1 + j];
        p[j] = s;
    }
#pragma unroll
    for (int j = 0; j < F1; j++) p[j] += __shfl_xor(p[j], 1);   // pair-combine
    float hh[F1];
#pragma unroll
    for (int j = 0; j < F1; j++) hh[j] = fmaxf(p[j] + sb1b[j], 0.0f); // relu∘relu

    float o[4];                                   // lane h owns outputs 4h..4h+3
#pragma unroll
    for (int jj = 0; jj < 4; jj++) {
        int j = 4*h + jj;
        float s = 0.0f;
#pragma unroll
        for (int k = 0; k < F1; k++) s += hh[k] * sW2a[k * F2 + j];
        o[jj] = s;
    }
    union { __half2 h2[2]; uint2 u2; } pk;
    pk.h2[0] = __float22half2_rn(make_float2(o[0], o[1]));
    pk.h2[1] = __float22half2_rn(make_float2(o[2], o[3]));
    h1wh[n * 2 + h] = pk.u2;                      // 8B/lane, pair-coalesced
}

// ==== kernel 3: layer-2 gather fp16 (2 lanes/node, 8B/lane) + MLP2 + pool ====
__global__ __launch_bounds__(256) void gin2pool_k(
    const uint2* __restrict__ h1wh, const int* __restrict__ np_g,
    const int* __restrict__ srcs, const float* __restrict__ b2a,
    const float* __restrict__ W2b, const float* __restrict__ b2b,
    const int* __restrict__ batch, float* __restrict__ gsum,
    float* __restrict__ gcnt) {
    __shared__ float sW2b[F2 * F2];
    __shared__ float sb2a[F2];
    __shared__ float sb2b[F2];
    __shared__ float ls[NGRAPH * F2];   // 512 > blockDim -> strided loops (r5 lesson)
    __shared__ float lc[NGRAPH];
    int t = threadIdx.x;
    if (t < F2 * F2) sW2b[t] = W2b[t];
    if (t < F2) { sb2a[t] = b2a[t]; sb2b[t] = b2b[t]; }
    for (int i = t; i < NGRAPH * F2; i += 256) ls[i] = 0.0f;
    if (t < NGRAPH) lc[t] = 0.0f;
    __syncthreads();

    int h = t & 1, slot = t >> 1;                 // 128 nodes per block
    int n = blockIdx.x * 128 + slot;
    if (n < N_NODES) {
        int b = n >> BSH, sl = n & (BSZ - 1);
        int pb = b * CAPB;
        int e  = pb + np_g[b * NPW + sl];
        int e1 = pb + np_g[b * NPW + sl + 1];

        float acc[4];
#pragma unroll
        for (int k = 0; k < 4; k++) acc[k] = 0.0f;
        for (; e + 4 <= e1; e += 4) {
            int s0 = srcs[e], s1 = srcs[e+1], s2 = srcs[e+2], s3 = srcs[e+3];
            uint2 v0 = h1wh[s0 * 2 + h];
            uint2 v1 = h1wh[s1 * 2 + h];
            uint2 v2 = h1wh[s2 * 2 + h];
            uint2 v3 = h1wh[s3 * 2 + h];
            acc4h(acc, v0); acc4h(acc, v1); acc4h(acc, v2); acc4h(acc, v3);
        }
        for (; e < e1; e++) acc4h(acc, h1wh[srcs[e] * 2 + h]);
        acc4h(acc, h1wh[n * 2 + h]);              // self term

        float u[4];
#pragma unroll
        for (int k = 0; k < 4; k++) u[k] = fmaxf(acc[k] + sb2a[4*h + k], 0.0f);

        float p[F2];
#pragma unroll
        for (int j = 0; j < F2; j++) {
            float s = 0.0f;
#pragma unroll
            for (int k = 0; k < 4; k++) s += u[k] * sW2b[(4*h + k) * F2 + j];
            p[j] = s;
        }
#pragma unroll
        for (int j = 0; j < F2; j++) p[j] += __shfl_xor(p[j], 1);

        int g = batch[n];
#pragma unroll
        for (int jj = 0; jj < 4; jj++) {          // lane h flushes feats 4h..4h+3
            int j = 4*h + jj;
            float v = fmaxf(p[j] + sb2b[j], 0.0f);
            atomicAdd(&ls[g * F2 + j], v);
        }
        if (h == 0) atomicAdd(&lc[g], 1.0f);
    }
    __syncthreads();
    for (int i = t; i < NGRAPH * F2; i += 256)
        if (ls[i] != 0.0f) atomicAdd(&gsum[i], ls[i]);
    if (t < NGRAPH && lc[t] != 0.0f) atomicAdd(&gcnt[t], lc[t]);
}

// ---------------- final: pooled -> FC -> log_softmax ----------------
__global__ void final_k(const float* __restrict__ gsum,
                        const float* __restrict__ gcnt,
                        const float* __restrict__ Wfc, const float* __restrict__ bfc,
                        float* __restrict__ out) {
    int g = threadIdx.x;
    if (g >= NGRAPH) return;
    float cnt = fmaxf(gcnt[g], 1.0f);
    float p[F2];
#pragma unroll
    for (int f = 0; f < F2; f++) p[f] = gsum[g * F2 + f] / cnt;
    float l[NCLS];
#pragma unroll
    for (int c = 0; c < NCLS; c++) {
        float s = bfc[c];
#pragma unroll
        for (int f = 0; f < F2; f++) s += p[f] * Wfc[f * NCLS + c];
        l[c] = s;
    }
    float m = -INFINITY;
#pragma unroll
    for (int c = 0; c < NCLS; c++) m = fmaxf(m, l[c]);
    float s = 0.0f;
#pragma unroll
    for (int c = 0; c < NCLS; c++) s += expf(l[c] - m);
    float lse = m + logf(s);
#pragma unroll
    for (int c = 0; c < NCLS; c++) out[g * NCLS + c] = l[c] - lse;
}

extern "C" void kernel_launch(void* const* d_in, const int* in_sizes, int n_in,
                              void* d_out, int out_size, void* d_ws, size_t ws_size,
                              hipStream_t stream) {
    const float* x    = (const float*)d_in[0];
    const int*   ei   = (const int*)d_in[1];   // [2, N_EDGES]
    const int*   batch= (const int*)d_in[2];   // [N_NODES], sorted
    const float* W1a  = (const float*)d_in[3];
    const float* b1a  = (const float*)d_in[4];
    const float* W1b  = (const float*)d_in[5];
    const float* b1b  = (const float*)d_in[6];
    const float* W2a  = (const float*)d_in[7];
    const float* b2a  = (const float*)d_in[8];
    const float* W2b  = (const float*)d_in[9];
    const float* b2b  = (const float*)d_in[10];
    const float* Wfc  = (const float*)d_in[11];
    const float* bfc  = (const float*)d_in[12];
    float* out = (float*)d_out;

    // workspace layout (4-byte units), ~20 MB
    float* ws      = (float*)d_ws;
    uint4* xw1h    = (uint4*)ws;                           // N_NODES*2 uint4 (fp16)
    uint2* h1wh    = (uint2*)(ws + (size_t)N_NODES * 8);   // N_NODES*2 uint2 (fp16)
    int*   pairs   = (int*)(ws + (size_t)N_NODES * 12);    // NBUK*CAPB = 1801728
    int*   srcs    = pairs + (size_t)NBUK * CAPB;          // NBUK*CAPB
    int*   np_g    = srcs + (size_t)NBUK * CAPB;           // NBUK*NPW = 100487
    int*   gcursor = np_g + (size_t)NBUK * NPW + 9;        // 512   (memset)
    float* gsum    = (float*)(gcursor + 512);              // 512   (memset)
    float* gcnt    = gsum + NGRAPH * F2;                   // 64    (memset)

    // one tiny memset: gcursor + gsum + gcnt adjacent
    hipMemsetAsync(gcursor, 0, (512 + NGRAPH * F2 + NGRAPH) * sizeof(int), stream);

    xpart_k<<<NBUK, 512, 0, stream>>>(x, W1a, xw1h, ei, gcursor, pairs);
    sortgin1_k<<<NBUK, 512, 0, stream>>>(xw1h, pairs, gcursor,
                                         b1a, W1b, b1b, W2a,
                                         h1wh, srcs, np_g);
    gin2pool_k<<<(N_NODES + 127) / 128, 256, 0, stream>>>(h1wh, np_g, srcs,
                                                          b2a, W2b, b2b, batch,
                                                          gsum, gcnt);
    final_k<<<1, 64, 0, stream>>>(gsum, gcnt, Wfc, bfc, out);
}

// Round 18
// 146.963 us; speedup vs baseline: 1.2374x; 1.0149x over previous
//
#include <hip/hip_runtime.h>
#include <hip/hip_fp16.h>
#include <math.h>

#define N_NODES 100000
#define N_EDGES 1600000
#define F0 32
#define F1 16
#define F2 8
#define NCLS 6
#define NGRAPH 64

#define BSH  8         // bucket = 256 nodes (power of 2 -> exact split)
#define BSZ  256       // nodes per bucket
#define NBUK 391       // ceil(100000/256)
#define CAPB 4608      // edge cap per bucket region (mean 4092, sigma 64 -> +8 sigma)
#define EPB  4093      // edges per xpart chunk: ceil(1600000/391)
#define XEIT 8         // xpart stage iterations: 8*512 = 4096 >= EPB
#define NPW  257       // np_g stride per bucket

// unpack 8 fp16 (uint4) into 8 float accumulators
__device__ __forceinline__ void acc8h(float* acc, uint4 v) {
    const __half2* p = reinterpret_cast<const __half2*>(&v);
#pragma unroll
    for (int q = 0; q < 4; q++) {
        float2 f = __half22float2(p[q]);
        acc[2*q]   += f.x;
        acc[2*q+1] += f.y;
    }
}
// unpack 4 fp16 (uint2) into 4 float accumulators
__device__ __forceinline__ void acc4h(float* acc, uint2 v) {
    const __half2* p = reinterpret_cast<const __half2*>(&v);
#pragma unroll
    for (int q = 0; q < 2; q++) {
        float2 f = __half22float2(p[q]);
        acc[2*q]   += f.x;
        acc[2*q+1] += f.y;
    }
}

// ====== kernel 1: node-transform (x@W1a -> fp16) + write-coalesced partition ======
// r18: wave-shfl scan (18 barriers -> 2) + projection split across lane pairs
__global__ __launch_bounds__(512) void xpart_k(
    const float* __restrict__ x, const float* __restrict__ W1a,
    uint4* __restrict__ xw1h, const int* __restrict__ ei,
    int* __restrict__ gcursor, int* __restrict__ pairs) {
    __shared__ float sW[F0 * F1];
    __shared__ int hist[512];              // counts -> excl (reused)
    __shared__ int gbase[512];
    __shared__ int lcur[512];
    __shared__ int wsum[8];
    __shared__ int lpk[4096];              // chunk edges, bucket-sorted (packed)
    __shared__ unsigned short lb[4096];    // bucket id per sorted edge
    int t = threadIdx.x, c = blockIdx.x;
    int lane = t & 63, w = t >> 6;
    for (int i = t; i < F0 * F1; i += 512) sW[i] = W1a[i];
    hist[t] = 0;
    __syncthreads();

    // --- stage src+dst in registers + chunk histogram ---
    int base = c * EPB;
    int dreg[XEIT], sreg[XEIT];
#pragma unroll
    for (int it = 0; it < XEIT; it++) {
        int li = it * 512 + t;
        int i = base + li;
        dreg[it] = -1;
        if (li < EPB && i < N_EDGES) {
            sreg[it] = ei[i];
            int d = ei[N_EDGES + i];
            dreg[it] = d;
            atomicAdd(&hist[d >> BSH], 1);
        }
    }

    // --- node projection: lane pair (2s,2s+1) per node; lane h holds xi half ---
    {
        int h = t & 1, s = t >> 1;
        int n = c * 256 + s;
        if (n < N_NODES) {
            const float4* xp = reinterpret_cast<const float4*>(x) + n * 8 + h * 4;
            float xi[16];
#pragma unroll
            for (int q = 0; q < 4; q++) {
                float4 v = xp[q];
                xi[4*q] = v.x; xi[4*q+1] = v.y; xi[4*q+2] = v.z; xi[4*q+3] = v.w;
            }
            float o[F1];
#pragma unroll
            for (int j = 0; j < F1; j++) {
                float s2 = 0.0f;
#pragma unroll
                for (int k = 0; k < 16; k++) s2 += xi[k] * sW[(16*h + k) * F1 + j];
                o[j] = s2;
            }
#pragma unroll
            for (int j = 0; j < F1; j++) o[j] += __shfl_xor(o[j], 1); // pair-combine
            union { __half2 h2[4]; uint4 u4; } pk;
#pragma unroll
            for (int jj = 0; jj < 4; jj++)
                pk.h2[jj] = __float22half2_rn(make_float2(o[8*h + 2*jj],
                                                          o[8*h + 2*jj + 1]));
            xw1h[n * 2 + h] = pk.u4;       // 16B/lane, pair-coalesced
        }
    }
    __syncthreads();

    // --- wave-shfl inclusive scan of hist (512 wide) ---
    int cntb = hist[t];
    int v = cntb;
#pragma unroll
    for (int off = 1; off < 64; off <<= 1) {
        int u = __shfl_up(v, off);
        if (lane >= off) v += u;
    }
    if (lane == 63) wsum[w] = v;
    __syncthreads();
    int woff = 0;
    for (int i = 0; i < w; i++) woff += wsum[i];
    int ex = v + woff - cntb;              // exclusive prefix
    lcur[t] = ex;
    gbase[t] = (t < NBUK) ? (t * CAPB + (cntb ? atomicAdd(&gcursor[t], cntb) : 0))
                          : 0;
    hist[t] = ex;                          // hist[] now holds excl[]
    __syncthreads();

    // --- place staged edges into LDS, sorted by bucket (pure LDS ops) ---
#pragma unroll
    for (int it = 0; it < XEIT; it++) {
        int d = dreg[it];
        if (d >= 0) {
            int b = d >> BSH;
            int slot = atomicAdd(&lcur[b], 1);
            lpk[slot] = ((d & (BSZ - 1)) << 17) | sreg[it];
            lb[slot] = (unsigned short)b;
        }
    }
    __syncthreads();

    // --- coalesced write-out: consecutive i -> consecutive addr within runs ---
    int tot = min(EPB, N_EDGES - base);
    for (int i = t; i < tot; i += 512) {
        int b = lb[i];
        int gpos = gbase[b] + (i - hist[b]);
        if (gpos < (b + 1) * CAPB)         // overflow guard (~never taken)
            pairs[gpos] = lpk[i];
    }
}

// ==== kernel 2: per-bucket counting sort (LDS, double-buffered) + gin1 ====
// r18: wave-shfl scan + srcs_s second buffer (drops register-stage + a barrier)
__global__ __launch_bounds__(512) void sortgin1_k(
    const uint4* __restrict__ xw1h, const int* __restrict__ pairs,
    const int* __restrict__ gcursor,
    const float* __restrict__ b1a, const float* __restrict__ W1b,
    const float* __restrict__ b1b, const float* __restrict__ W2a,
    uint2* __restrict__ h1wh, int* __restrict__ srcs,
    int* __restrict__ np_g) {
    __shared__ int hist[256];
    __shared__ int cur[256];
    __shared__ int np[BSZ + 1];
    __shared__ int wsum[4];
    __shared__ int srcs_l[CAPB];           // staged packed pairs
    __shared__ int srcs_s[CAPB];           // sorted srcs
    __shared__ float sW1b[F1 * F1];
    __shared__ float sW2a[F1 * F2];
    __shared__ float sb1a[F1], sb1b[F1];
    int t = threadIdx.x, b = blockIdx.x;
    int lane = t & 63, w = t >> 6;
    if (t < F1 * F1) sW1b[t] = W1b[t];
    if (t < F1 * F2) sW2a[t] = W2a[t];
    if (t < F1) { sb1a[t] = b1a[t]; sb1b[t] = b1b[t]; }
    if (t < 256) hist[t] = 0;
    __syncthreads();

    int cnt = min(gcursor[b], CAPB);
    int pb = b * CAPB;
    // hist + stage packed pairs into LDS (single global read of pairs)
    for (int i = t; i < cnt; i += 512) {
        int p = pairs[pb + i];
        srcs_l[i] = p;
        atomicAdd(&hist[p >> 17], 1);
    }
    __syncthreads();

    // --- wave-shfl inclusive scan of hist (256 wide: waves 0-3) ---
    int cntv = (t < 256) ? hist[t] : 0;
    int v = cntv;
    if (t < 256) {
#pragma unroll
        for (int off = 1; off < 64; off <<= 1) {
            int u = __shfl_up(v, off);
            if (lane >= off) v += u;
        }
        if (lane == 63) wsum[w] = v;
    }
    __syncthreads();
    if (t < 256) {
        int woff = 0;
        for (int i = 0; i < w; i++) woff += wsum[i];
        int excl = v + woff - cntv;
        np[t] = excl;
        cur[t] = excl;
        np_g[b * NPW + t] = excl;
        if (t == 0) { np[BSZ] = cnt; np_g[b * NPW + BSZ] = cnt; }
    }
    __syncthreads();

    // scatter into second buffer (no read/write race, no register staging)
    for (int i = t; i < cnt; i += 512) {
        int p = srcs_l[i];
        int pos = atomicAdd(&cur[p >> 17], 1);
        srcs_s[pos] = p & 0x1FFFF;
    }
    __syncthreads();
    // coalesced persist for gin2: consecutive lanes -> consecutive addresses
    for (int i = t; i < cnt; i += 512) srcs[pb + i] = srcs_s[i];

    // ---- layer-1 gather: 2 lanes/node, 16B/lane, rows L2-resident fp16 ----
    int h = t & 1, slot = t >> 1;
    int n = b * BSZ + slot;
    if (n >= N_NODES) return;
    int e  = np[slot];
    int e1 = np[slot + 1];

    float acc[8];
#pragma unroll
    for (int k = 0; k < 8; k++) acc[k] = 0.0f;
    for (; e + 4 <= e1; e += 4) {                 // 4 rows in flight
        int s0 = srcs_s[e], s1 = srcs_s[e+1], s2 = srcs_s[e+2], s3 = srcs_s[e+3];
        uint4 v0 = xw1h[s0 * 2 + h];
        uint4 v1 = xw1h[s1 * 2 + h];
        uint4 v2 = xw1h[s2 * 2 + h];
        uint4 v3 = xw1h[s3 * 2 + h];
        acc8h(acc, v0); acc8h(acc, v1); acc8h(acc, v2); acc8h(acc, v3);
    }
    for (; e < e1; e++) acc8h(acc, xw1h[srcs_s[e] * 2 + h]);
    acc8h(acc, xw1h[n * 2 + h]);                  // self term

    float u[8];
#pragma unroll
    for (int k = 0; k < 8; k++) u[k] = fmaxf(acc[k] + sb1a[8*h + k], 0.0f);

    float p[F1];
#pragma unroll
    for (int j = 0; j < F1; j++) {
        float s = 0.0f;
#pragma unroll
        for (int k = 0; k < 8; k++) s += u[k] * sW1b[(8*h + k) * F1 + j];
        p[j] = s;
    }
#pragma unroll
    for (int j = 0; j < F1; j++) p[j] += __shfl_xor(p[j], 1);   // pair-combine
    float hh[F1];
#pragma unroll
    for (int j = 0; j < F1; j++) hh[j] = fmaxf(p[j] + sb1b[j], 0.0f); // relu∘relu

    float o[4];                                   // lane h owns outputs 4h..4h+3
#pragma unroll
    for (int jj = 0; jj < 4; jj++) {
        int j = 4*h + jj;
        float s = 0.0f;
#pragma unroll
        for (int k = 0; k < F1; k++) s += hh[k] * sW2a[k * F2 + j];
        o[jj] = s;
    }
    union { __half2 h2[2]; uint2 u2; } pk;
    pk.h2[0] = __float22half2_rn(make_float2(o[0], o[1]));
    pk.h2[1] = __float22half2_rn(make_float2(o[2], o[3]));
    h1wh[n * 2 + h] = pk.u2;                      // 8B/lane, pair-coalesced
}

// ==== kernel 3: layer-2 gather fp16 (2 lanes/node, 8B/lane) + MLP2 + pool ====
__global__ __launch_bounds__(256) void gin2pool_k(
    const uint2* __restrict__ h1wh, const int* __restrict__ np_g,
    const int* __restrict__ srcs, const float* __restrict__ b2a,
    const float* __restrict__ W2b, const float* __restrict__ b2b,
    const int* __restrict__ batch, float* __restrict__ gsum,
    float* __restrict__ gcnt) {
    __shared__ float sW2b[F2 * F2];
    __shared__ float sb2a[F2];
    __shared__ float sb2b[F2];
    __shared__ float ls[NGRAPH * F2];   // 512 > blockDim -> strided loops (r5 lesson)
    __shared__ float lc[NGRAPH];
    int t = threadIdx.x;
    if (t < F2 * F2) sW2b[t] = W2b[t];
    if (t < F2) { sb2a[t] = b2a[t]; sb2b[t] = b2b[t]; }
    for (int i = t; i < NGRAPH * F2; i += 256) ls[i] = 0.0f;
    if (t < NGRAPH) lc[t] = 0.0f;
    __syncthreads();

    int h = t & 1, slot = t >> 1;                 // 128 nodes per block
    int n = blockIdx.x * 128 + slot;
    if (n < N_NODES) {
        int b = n >> BSH, sl = n & (BSZ - 1);
        int pb = b * CAPB;
        int e  = pb + np_g[b * NPW + sl];
        int e1 = pb + np_g[b * NPW + sl + 1];

        float acc[4];
#pragma unroll
        for (int k = 0; k < 4; k++) acc[k] = 0.0f;
        for (; e + 4 <= e1; e += 4) {
            int s0 = srcs[e], s1 = srcs[e+1], s2 = srcs[e+2], s3 = srcs[e+3];
            uint2 v0 = h1wh[s0 * 2 + h];
            uint2 v1 = h1wh[s1 * 2 + h];
            uint2 v2 = h1wh[s2 * 2 + h];
            uint2 v3 = h1wh[s3 * 2 + h];
            acc4h(acc, v0); acc4h(acc, v1); acc4h(acc, v2); acc4h(acc, v3);
        }
        for (; e < e1; e++) acc4h(acc, h1wh[srcs[e] * 2 + h]);
        acc4h(acc, h1wh[n * 2 + h]);              // self term

        float u[4];
#pragma unroll
        for (int k = 0; k < 4; k++) u[k] = fmaxf(acc[k] + sb2a[4*h + k], 0.0f);

        float p[F2];
#pragma unroll
        for (int j = 0; j < F2; j++) {
            float s = 0.0f;
#pragma unroll
            for (int k = 0; k < 4; k++) s += u[k] * sW2b[(4*h + k) * F2 + j];
            p[j] = s;
        }
#pragma unroll
        for (int j = 0; j < F2; j++) p[j] += __shfl_xor(p[j], 1);

        int g = batch[n];
#pragma unroll
        for (int jj = 0; jj < 4; jj++) {          // lane h flushes feats 4h..4h+3
            int j = 4*h + jj;
            float v = fmaxf(p[j] + sb2b[j], 0.0f);
            atomicAdd(&ls[g * F2 + j], v);
        }
        if (h == 0) atomicAdd(&lc[g], 1.0f);
    }
    __syncthreads();
    for (int i = t; i < NGRAPH * F2; i += 256)
        if (ls[i] != 0.0f) atomicAdd(&gsum[i], ls[i]);
    if (t < NGRAPH && lc[t] != 0.0f) atomicAdd(&gcnt[t], lc[t]);
}

// ---------------- final: pooled -> FC -> log_softmax ----------------
__global__ void final_k(const float* __restrict__ gsum,
                        const float* __restrict__ gcnt,
                        const float* __restrict__ Wfc, const float* __restrict__ bfc,
                        float* __restrict__ out) {
    int g = threadIdx.x;
    if (g >= NGRAPH) return;
    float cnt = fmaxf(gcnt[g], 1.0f);
    float p[F2];
#pragma unroll
    for (int f = 0; f < F2; f++) p[f] = gsum[g * F2 + f] / cnt;
    float l[NCLS];
#pragma unroll
    for (int c = 0; c < NCLS; c++) {
        float s = bfc[c];
#pragma unroll
        for (int f = 0; f < F2; f++) s += p[f] * Wfc[f * NCLS + c];
        l[c] = s;
    }
    float m = -INFINITY;
#pragma unroll
    for (int c = 0; c < NCLS; c++) m = fmaxf(m, l[c]);
    float s = 0.0f;
#pragma unroll
    for (int c = 0; c < NCLS; c++) s += expf(l[c] - m);
    float lse = m + logf(s);
#pragma unroll
    for (int c = 0; c < NCLS; c++) out[g * NCLS + c] = l[c] - lse;
}

extern "C" void kernel_launch(void* const* d_in, const int* in_sizes, int n_in,
                              void* d_out, int out_size, void* d_ws, size_t ws_size,
                              hipStream_t stream) {
    const float* x    = (const float*)d_in[0];
    const int*   ei   = (const int*)d_in[1];   // [2, N_EDGES]
    const int*   batch= (const int*)d_in[2];   // [N_NODES], sorted
    const float* W1a  = (const float*)d_in[3];
    const float* b1a  = (const float*)d_in[4];
    const float* W1b  = (const float*)d_in[5];
    const float* b1b  = (const float*)d_in[6];
    const float* W2a  = (const float*)d_in[7];
    const float* b2a  = (const float*)d_in[8];
    const float* W2b  = (const float*)d_in[9];
    const float* b2b  = (const float*)d_in[10];
    const float* Wfc  = (const float*)d_in[11];
    const float* bfc  = (const float*)d_in[12];
    float* out = (float*)d_out;

    // workspace layout (4-byte units), ~20 MB
    float* ws      = (float*)d_ws;
    uint4* xw1h    = (uint4*)ws;                           // N_NODES*2 uint4 (fp16)
    uint2* h1wh    = (uint2*)(ws + (size_t)N_NODES * 8);   // N_NODES*2 uint2 (fp16)
    int*   pairs   = (int*)(ws + (size_t)N_NODES * 12);    // NBUK*CAPB = 1801728
    int*   srcs    = pairs + (size_t)NBUK * CAPB;          // NBUK*CAPB
    int*   np_g    = srcs + (size_t)NBUK * CAPB;           // NBUK*NPW = 100487
    int*   gcursor = np_g + (size_t)NBUK * NPW + 9;        // 512   (memset)
    float* gsum    = (float*)(gcursor + 512);              // 512   (memset)
    float* gcnt    = gsum + NGRAPH * F2;                   // 64    (memset)

    // one tiny memset: gcursor + gsum + gcnt adjacent
    hipMemsetAsync(gcursor, 0, (512 + NGRAPH * F2 + NGRAPH) * sizeof(int), stream);

    xpart_k<<<NBUK, 512, 0, stream>>>(x, W1a, xw1h, ei, gcursor, pairs);
    sortgin1_k<<<NBUK, 512, 0, stream>>>(xw1h, pairs, gcursor,
                                         b1a, W1b, b1b, W2a,
                                         h1wh, srcs, np_g);
    gin2pool_k<<<(N_NODES + 127) / 128, 256, 0, stream>>>(h1wh, np_g, srcs,
                                                          b2a, W2b, b2b, batch,
                                                          gsum, gcnt);
    final_k<<<1, 64, 0, stream>>>(gsum, gcnt, Wfc, bfc, out);
}